// Round 5
// baseline (361.835 us; speedup 1.0000x reference)
//
#include <hip/hip_runtime.h>
#include <hip/hip_bf16.h>

#define NN 51200
#define EE 819200
#define BB 64
#define NS 32
#define NPW 16      // nodes per wave in edge passes
#define NBUCK 512   // dst-range buckets for scatter
#define NPB 100     // nodes per bucket = NN/NBUCK

typedef __attribute__((ext_vector_type(8))) short short8;
typedef __attribute__((ext_vector_type(4))) float f32x4;

__device__ __forceinline__ ushort f2bf(float f) {
    unsigned int u = __float_as_uint(f);
    unsigned int r = (u + 0x7FFFu + ((u >> 16) & 1u)) >> 16;   // RNE, finite inputs
    return (ushort)r;
}
__device__ __forceinline__ unsigned int cvt_pk_bf16(float lo, float hi) {
    unsigned int r;
    asm("v_cvt_pk_bf16_f32 %0, %1, %2" : "=v"(r) : "v"(lo), "v"(hi));
    return r;
}

// ---------------- weight prep ----------------
__global__ void prep_weights(const float* __restrict__ gW1, const float* __restrict__ lW1,
                             ushort* __restrict__ W1p, ushort* __restrict__ L1p) {
    int tid = threadIdx.x;
    for (int idx = tid; idx < 64 * 256; idx += 512) {
        int i = idx & 7, c = (idx >> 3) & 255, q = idx >> 11;
        int k = (q >> 2) * 32 + (q & 3) * 8 + i;
        W1p[idx] = f2bf(c < 128 ? gW1[k * 128 + c] : gW1[(64 + k) * 128 + (c - 128)]);
        L1p[idx] = f2bf(c < 128 ? lW1[k * 128 + c] : lW1[(128 + k) * 128 + (c - 128)]);
    }
}

// ---------------- CSR build ----------------
__global__ void hist_kernel(const int* __restrict__ eidx, int* __restrict__ cnt) {
    int i = blockIdx.x * 256 + threadIdx.x;
    atomicAdd(&cnt[eidx[EE + i]], 1);
}

__global__ __launch_bounds__(1024) void prefix_kernel(const int* __restrict__ cnt,
                                                      int* __restrict__ offs,
                                                      int* __restrict__ cursor,
                                                      int* __restrict__ bcur) {
    __shared__ int sps[1024];
    const int t = threadIdx.x;
    const int base = t * 50;            // 51200 / 1024
    int sum = 0;
    for (int j = 0; j < 50; ++j) sum += cnt[base + j];
    sps[t] = sum;
    __syncthreads();
    for (int o = 1; o < 1024; o <<= 1) {
        int v = (t >= o) ? sps[t - o] : 0;
        __syncthreads();
        sps[t] += v;
        __syncthreads();
    }
    int run = sps[t] - sum;             // exclusive prefix
    for (int j = 0; j < 50; ++j) {
        int node = base + j;
        offs[node] = run;
        cursor[node] = run;
        if (node % NPB == 0) bcur[(node / NPB) * 16] = run;   // bucket start cursor (line-padded)
        run += cnt[node];
    }
    if (t == 1023) offs[NN] = EE;
}

// phase A: bin (src,dst) into dst-range buckets (btmp overlays PQ region — consumed before pq_gemm)
__global__ void bucketA_kernel(const int* __restrict__ eidx, int* __restrict__ bcur,
                               int2* __restrict__ btmp) {
    int i = blockIdx.x * 256 + threadIdx.x;
    int d = eidx[EE + i], s = eidx[i];
    int pos = atomicAdd(&bcur[(d / NPB) * 16], 1);
    btmp[pos] = make_int2(s, d);
}

// phase B: per-bucket placement — csr writes land in a ~6.4 KB window per block
__global__ __launch_bounds__(256) void bucketB_kernel(const int2* __restrict__ btmp,
                                                      const int* __restrict__ offs,
                                                      int* __restrict__ cursor,
                                                      int* __restrict__ csr) {
    const int bkt = blockIdx.x;
    const int begin = offs[bkt * NPB], end = offs[(bkt + 1) * NPB];
    for (int i = begin + threadIdx.x; i < end; i += 256) {
        int2 p = btmp[i];
        int pos = atomicAdd(&cursor[p.y], 1);
        csr[pos] = p.x;
    }
}

// ---------------- node-table GEMM: out[n][0:256] = bf16( x[n]@Wcat + bias_fold + T12[batch[n]] ) ----------------
__global__ __launch_bounds__(512) void pq_gemm(
        const float* __restrict__ x, const ushort* __restrict__ Wp,
        const float* __restrict__ bias1, const float* __restrict__ T12,
        const int* __restrict__ batch, ushort* __restrict__ out) {
    const int tid = threadIdx.x;
    const int w = tid >> 6, l = tid & 63, lr = l & 15, lg = l >> 4;
    const int node = blockIdx.x * 128 + w * 16 + lr;

    short8 xa[2];
#pragma unroll
    for (int ks = 0; ks < 2; ++ks) {
        const float4* bp = reinterpret_cast<const float4*>(x + (long)node * 64 + ks * 32 + lg * 8);
        float4 f0 = bp[0], f1 = bp[1];
        union { short8 s; unsigned int u[4]; } t;
        t.u[0] = cvt_pk_bf16(f0.x, f0.y);
        t.u[1] = cvt_pk_bf16(f0.z, f0.w);
        t.u[2] = cvt_pk_bf16(f1.x, f1.y);
        t.u[3] = cvt_pk_bf16(f1.z, f1.w);
        xa[ks] = t.s;
    }
    f32x4 acc[16];
#pragma unroll
    for (int t = 0; t < 16; ++t)
#pragma unroll
        for (int i = 0; i < 4; ++i)
            acc[t][i] = (t < 8) ? bias1[t * 16 + lg * 4 + i] : 0.f;
#pragma unroll
    for (int ks = 0; ks < 2; ++ks)
#pragma unroll
        for (int t = 0; t < 16; ++t) {
            short8 wf = *reinterpret_cast<const short8*>(Wp + (((ks * 4 + lg) * 256) + t * 16 + lr) * 8);
            acc[t] = __builtin_amdgcn_mfma_f32_16x16x32_bf16(wf, xa[ks], acc[t], 0, 0, 0);
        }
    if (T12) {
        const float* tp = T12 + (long)batch[node] * 256;
#pragma unroll
        for (int t = 0; t < 16; ++t)
#pragma unroll
            for (int i = 0; i < 4; ++i)
                acc[t][i] += tp[t * 16 + lg * 4 + i];
    }
#pragma unroll
    for (int t = 0; t < 16; ++t) {
        uint2 v;
        v.x = cvt_pk_bf16(acc[t][0], acc[t][1]);
        v.y = cvt_pk_bf16(acc[t][2], acc[t][3]);
        *reinterpret_cast<uint2*>(out + (long)node * 256 + t * 16 + lg * 4) = v;
    }
}

// ---------------- global edge pass (CSR): reg-accumulated pooling ----------------
__global__ __launch_bounds__(256) void global_edge(
        const ushort* __restrict__ PQ, const int* __restrict__ csr,
        const int* __restrict__ offs, const float* __restrict__ e,
        const int* __restrict__ batch,
        float* __restrict__ hidpart, float* __restrict__ esumpart) {
    const int tid = threadIdx.x;
    const int w = tid >> 6, l = tid & 63;
    const int wid = blockIdx.x * 4 + w;
    const int node0 = wid * NPW;
    const int slot = wid & (NS - 1);

    const int offv = offs[node0 + ((l < 17) ? l : 16)];
    const float evv = e[node0 + (l & 15)];
    const int bv = batch[node0 + (l & 15)];

    float accp0 = 0.f, accp1 = 0.f, eacc = 0.f;
    int curb = __shfl(bv, 0, 64);

    for (int n = 0; n < NPW; ++n) {
        const int off = __shfl(offv, n, 64);
        const int cnt = __shfl(offv, n + 1, 64) - off;
        const int bb  = __shfl(bv, n, 64);
        const float ev = __shfl(evv, n, 64);
        if (bb != curb) {
            float* hp = hidpart + (long)slot * (BB * 128) + curb * 128;
            atomicAdd(hp + 2 * l, accp0);
            atomicAdd(hp + 2 * l + 1, accp1);
            if (l == 0) atomicAdd(&esumpart[slot * BB + curb], eacc);
            accp0 = accp1 = eacc = 0.f;
            curb = bb;
        }
        if (cnt <= 0) continue;
        const unsigned int pdu = *reinterpret_cast<const unsigned int*>(PQ + (long)(node0 + n) * 256 + 2 * l);
        const float p0 = __uint_as_float(pdu << 16);
        const float p1 = __uint_as_float(pdu & 0xFFFF0000u);
        float h0 = 0.f, h1 = 0.f;
        for (int g0 = 0; g0 < cnt; g0 += 64) {
            int m = cnt - g0; if (m > 64) m = 64;
            const int srcv = csr[off + g0 + ((l < m) ? l : (m - 1))];
            for (int jj = 0; jj < m; jj += 8) {
                unsigned int qv[8];
#pragma unroll
                for (int k = 0; k < 8; ++k) {
                    int kk = jj + k; if (kk > m - 1) kk = m - 1;
                    const int s = __shfl(srcv, kk, 64);
                    qv[k] = *reinterpret_cast<const unsigned int*>(PQ + (long)s * 256 + 128 + 2 * l);
                }
#pragma unroll
                for (int k = 0; k < 8; ++k) {
                    const float q0 = __uint_as_float(qv[k] << 16);
                    const float q1 = __uint_as_float(qv[k] & 0xFFFF0000u);
                    const float r0 = fmaxf(p0 + q0, 0.f);
                    const float r1 = fmaxf(p1 + q1, 0.f);
                    if (jj + k < m) { h0 += r0; h1 += r1; }
                }
            }
        }
        accp0 += ev * h0; accp1 += ev * h1; eacc += ev * (float)cnt;
    }
    {
        float* hp = hidpart + (long)slot * (BB * 128) + curb * 128;
        atomicAdd(hp + 2 * l, accp0);
        atomicAdd(hp + 2 * l + 1, accp1);
        if (l == 0) atomicAdd(&esumpart[slot * BB + curb], eacc);
    }
}

// ---------------- fused: hidsum reduce -> pooled (LDS only) -> T12 ----------------
// grid = BB blocks, 256 threads
__global__ __launch_bounds__(256) void pooled_t12_kernel(
        const float* __restrict__ hidpart, const float* __restrict__ esumpart,
        const float* __restrict__ gW2, const float* __restrict__ gb2,
        const float* __restrict__ lW1, float* __restrict__ T12) {
    __shared__ float hs[128];
    __shared__ float qacc[4][64];
    __shared__ float pb[64];
    __shared__ float esv;
    const int b = blockIdx.x, tid = threadIdx.x;
    if (tid < 128) {
        float s = 0.f;
        for (int sl = 0; sl < NS; ++sl) s += hidpart[(long)sl * (BB * 128) + b * 128 + tid];
        hs[tid] = s;
    } else if (tid == 128) {
        float s = 0.f;
        for (int sl = 0; sl < NS; ++sl) s += esumpart[sl * BB + b];
        esv = s;
    }
    __syncthreads();
    {   // pooled[b][col], 4 threads per column over k-quarters
        int col = tid & 63, qr = tid >> 6;
        float a = 0.f;
        for (int k = qr * 32; k < qr * 32 + 32; ++k) a += hs[k] * gW2[k * 64 + col];
        qacc[qr][col] = a;
    }
    __syncthreads();
    if (tid < 64) pb[tid] = qacc[0][tid] + qacc[1][tid] + qacc[2][tid] + qacc[3][tid] + esv * gb2[tid];
    __syncthreads();
    // T12[b][c2] = pooled[b] @ lW1 scalar-part columns
    const float* col = (tid < 128) ? (lW1 + 64 * 128 + tid) : (lW1 + 192 * 128 + (tid - 128));
    float acc = 0.f;
    for (int k = 0; k < 64; ++k) acc += pb[k] * col[k * 128];
    T12[b * 256 + tid] = acc;
}

// ---------------- local edge pass (CSR): out[n] = sum_src relu(PL[n]+QL[src])·w2 + cnt*b2 ----------------
__global__ __launch_bounds__(256) void local_edge(
        const ushort* __restrict__ PQL, const int* __restrict__ csr,
        const int* __restrict__ offs, const float* __restrict__ lW2,
        const float* __restrict__ lb2, float* __restrict__ out) {
    const int tid = threadIdx.x;
    const int w = tid >> 6, l = tid & 63;
    const int wid = blockIdx.x * 4 + w;
    const int node0 = wid * NPW;
    const int offv = offs[node0 + ((l < 17) ? l : 16)];
    const float w20 = lW2[2 * l], w21 = lW2[2 * l + 1];
    const float b2v = lb2[0];

    for (int n = 0; n < NPW; ++n) {
        const int off = __shfl(offv, n, 64);
        const int cnt = __shfl(offv, n + 1, 64) - off;
        float dacc = 0.f;
        if (cnt > 0) {
            const unsigned int pdu = *reinterpret_cast<const unsigned int*>(PQL + (long)(node0 + n) * 256 + 2 * l);
            const float p0 = __uint_as_float(pdu << 16);
            const float p1 = __uint_as_float(pdu & 0xFFFF0000u);
            for (int g0 = 0; g0 < cnt; g0 += 64) {
                int m = cnt - g0; if (m > 64) m = 64;
                const int srcv = csr[off + g0 + ((l < m) ? l : (m - 1))];
                for (int jj = 0; jj < m; jj += 8) {
                    unsigned int qv[8];
#pragma unroll
                    for (int k = 0; k < 8; ++k) {
                        int kk = jj + k; if (kk > m - 1) kk = m - 1;
                        const int s = __shfl(srcv, kk, 64);
                        qv[k] = *reinterpret_cast<const unsigned int*>(PQL + (long)s * 256 + 128 + 2 * l);
                    }
#pragma unroll
                    for (int k = 0; k < 8; ++k) {
                        const float q0 = __uint_as_float(qv[k] << 16);
                        const float q1 = __uint_as_float(qv[k] & 0xFFFF0000u);
                        const float t0 = fmaxf(p0 + q0, 0.f) * w20 + fmaxf(p1 + q1, 0.f) * w21;
                        if (jj + k < m) dacc += t0;
                    }
                }
            }
            dacc += __shfl_xor(dacc, 1, 64);
            dacc += __shfl_xor(dacc, 2, 64);
            dacc += __shfl_xor(dacc, 4, 64);
            dacc += __shfl_xor(dacc, 8, 64);
            dacc += __shfl_xor(dacc, 16, 64);
            dacc += __shfl_xor(dacc, 32, 64);
        }
        if (l == 0) out[node0 + n] = dacc + (float)cnt * b2v;
    }
}

extern "C" void kernel_launch(void* const* d_in, const int* in_sizes, int n_in,
                              void* d_out, int out_size, void* d_ws, size_t ws_size,
                              hipStream_t stream) {
    const float* x   = (const float*)d_in[0];
    const float* e   = (const float*)d_in[1];
    const int*   ei  = (const int*)d_in[2];
    const int*   bat = (const int*)d_in[3];
    const float* gW1 = (const float*)d_in[4];
    const float* gb1 = (const float*)d_in[5];
    const float* gW2 = (const float*)d_in[6];
    const float* gb2 = (const float*)d_in[7];
    const float* lW1 = (const float*)d_in[8];
    const float* lb1 = (const float*)d_in[9];
    const float* lW2 = (const float*)d_in[10];
    const float* lb2 = (const float*)d_in[11];

    char* ws = (char*)d_ws;
    ushort* W1p     = (ushort*)(ws);                     //    32768 B
    ushort* L1p     = (ushort*)(ws + 32768);             //    32768 B
    float*  T12     = (float*)(ws + 65536);              //    65536 B
    float*  esumpart= (float*)(ws + 131072);             //     8192 B
    float*  hidpart = (float*)(ws + 139264);             //  1048576 B
    int*    counts  = (int*)(ws + 1187840);              //   204800 B
    int*    offs    = (int*)(ws + 1392640);              //   204816 B (51201 ints)
    int*    cursor  = (int*)(ws + 1597456);              //   204800 B
    int*    bcur    = (int*)(ws + 1802256);              //    32768 B (512 line-padded)
    int*    csr     = (int*)(ws + 1835024);              //  3276800 B
    ushort* PQ      = (ushort*)(ws + 5111824);           // 26214400 B (btmp overlays; reused for PQL)
    int2*   btmp    = (int2*)PQ;                         // 6553600 B, consumed before pq_gemm

    hipMemsetAsync(counts, 0, 204800, stream);
    hipMemsetAsync(esumpart, 0, 8192 + 1048576, stream);           // esumpart + hidpart
    hipMemsetAsync(d_out, 0, (size_t)out_size * sizeof(float), stream);

    prep_weights<<<1, 512, 0, stream>>>(gW1, lW1, W1p, L1p);
    hist_kernel<<<EE / 256, 256, 0, stream>>>(ei, counts);
    prefix_kernel<<<1, 1024, 0, stream>>>(counts, offs, cursor, bcur);
    bucketA_kernel<<<EE / 256, 256, 0, stream>>>(ei, bcur, btmp);
    bucketB_kernel<<<NBUCK, 256, 0, stream>>>(btmp, offs, cursor, csr);

    pq_gemm<<<NN / 128, 512, 0, stream>>>(x, W1p, gb1, nullptr, bat, PQ);
    global_edge<<<NN / (4 * NPW), 256, 0, stream>>>(PQ, csr, offs, e, bat, hidpart, esumpart);
    pooled_t12_kernel<<<BB, 256, 0, stream>>>(hidpart, esumpart, gW2, gb2, lW1, T12);
    pq_gemm<<<NN / 128, 512, 0, stream>>>(x, L1p, lb1, T12, bat, PQ);   // -> PQL
    local_edge<<<NN / (4 * NPW), 256, 0, stream>>>(PQ, csr, offs, lW2, lb2, (float*)d_out);
}

// Round 6
// 275.051 us; speedup vs baseline: 1.3155x; 1.3155x over previous
//
#include <hip/hip_runtime.h>
#include <hip/hip_bf16.h>

#define NN 51200
#define EE 819200
#define BB 64
#define NS 32
#define NPW 16      // nodes per wave in edge passes
#define NBUCK 512   // dst-range buckets for scatter
#define NPB 100     // nodes per bucket = NN/NBUCK
#define NCHUNK 200  // scan chunks = NN/256

typedef __attribute__((ext_vector_type(8))) short short8;
typedef __attribute__((ext_vector_type(4))) float f32x4;

__device__ __forceinline__ ushort f2bf(float f) {
    unsigned int u = __float_as_uint(f);
    unsigned int r = (u + 0x7FFFu + ((u >> 16) & 1u)) >> 16;   // RNE, finite inputs
    return (ushort)r;
}
__device__ __forceinline__ unsigned int cvt_pk_bf16(float lo, float hi) {
    unsigned int r;
    asm("v_cvt_pk_bf16_f32 %0, %1, %2" : "=v"(r) : "v"(lo), "v"(hi));
    return r;
}

// ---------------- weight prep ----------------
__global__ void prep_weights(const float* __restrict__ gW1, const float* __restrict__ lW1,
                             ushort* __restrict__ W1p, ushort* __restrict__ L1p) {
    int tid = threadIdx.x;
    for (int idx = tid; idx < 64 * 256; idx += 512) {
        int i = idx & 7, c = (idx >> 3) & 255, q = idx >> 11;
        int k = (q >> 2) * 32 + (q & 3) * 8 + i;
        W1p[idx] = f2bf(c < 128 ? gW1[k * 128 + c] : gW1[(64 + k) * 128 + (c - 128)]);
        L1p[idx] = f2bf(c < 128 ? lW1[k * 128 + c] : lW1[(128 + k) * 128 + (c - 128)]);
    }
}

// ---------------- CSR build ----------------
__global__ void hist_kernel(const int* __restrict__ eidx, int* __restrict__ cnt) {
    int i = blockIdx.x * 256 + threadIdx.x;
    atomicAdd(&cnt[eidx[EE + i]], 1);
}

// level 1: per-256-node chunk sums
__global__ __launch_bounds__(256) void chunk_sum_kernel(const int* __restrict__ cnt,
                                                        int* __restrict__ csum) {
    __shared__ int red[4];
    const int t = threadIdx.x;
    int v = cnt[blockIdx.x * 256 + t];
#pragma unroll
    for (int m = 1; m < 64; m <<= 1) v += __shfl_xor(v, m, 64);
    if ((t & 63) == 0) red[t >> 6] = v;
    __syncthreads();
    if (t == 0) csum[blockIdx.x] = red[0] + red[1] + red[2] + red[3];
}

// level 2: scan the 200 chunk sums (exclusive)
__global__ __launch_bounds__(256) void chunk_scan_kernel(const int* __restrict__ csum,
                                                         int* __restrict__ cbase) {
    __shared__ int s[256];
    const int t = threadIdx.x;
    int v = (t < NCHUNK) ? csum[t] : 0;
    s[t] = v;
    __syncthreads();
    for (int o = 1; o < 256; o <<= 1) {
        int u = (t >= o) ? s[t - o] : 0;
        __syncthreads();
        s[t] += u;
        __syncthreads();
    }
    if (t < NCHUNK) cbase[t] = s[t] - v;
}

// level 3: in-chunk exclusive scan + base -> offs/cursor/bcur
__global__ __launch_bounds__(256) void offs_kernel(const int* __restrict__ cnt,
                                                   const int* __restrict__ cbase,
                                                   int* __restrict__ offs,
                                                   int* __restrict__ cursor,
                                                   int* __restrict__ bcur) {
    __shared__ int s[256];
    const int t = threadIdx.x;
    const int node = blockIdx.x * 256 + t;
    const int c = cnt[node];
    s[t] = c;
    __syncthreads();
    for (int o = 1; o < 256; o <<= 1) {
        int u = (t >= o) ? s[t - o] : 0;
        __syncthreads();
        s[t] += u;
        __syncthreads();
    }
    const int run = cbase[blockIdx.x] + s[t] - c;   // exclusive prefix
    offs[node] = run;
    cursor[node] = run;
    if (node % NPB == 0) bcur[(node / NPB) * 16] = run;
    if (node == NN - 1) offs[NN] = EE;
}

// phase A: bin (src,dst) into dst-range buckets (btmp overlays PQ region — consumed before pq_gemm)
__global__ void bucketA_kernel(const int* __restrict__ eidx, int* __restrict__ bcur,
                               int2* __restrict__ btmp) {
    int i = blockIdx.x * 256 + threadIdx.x;
    int d = eidx[EE + i], s = eidx[i];
    int pos = atomicAdd(&bcur[(d / NPB) * 16], 1);
    btmp[pos] = make_int2(s, d);
}

// phase B: per-bucket placement — csr writes land in a ~6.4 KB window per block
__global__ __launch_bounds__(256) void bucketB_kernel(const int2* __restrict__ btmp,
                                                      const int* __restrict__ offs,
                                                      int* __restrict__ cursor,
                                                      int* __restrict__ csr) {
    const int bkt = blockIdx.x;
    const int begin = offs[bkt * NPB], end = offs[(bkt + 1) * NPB];
    for (int i = begin + threadIdx.x; i < end; i += 256) {
        int2 p = btmp[i];
        int pos = atomicAdd(&cursor[p.y], 1);
        csr[pos] = p.x;
    }
}

// ---------------- node-table GEMM: out[n][0:256] = bf16( x[n]@Wcat + bias_fold + T12[batch[n]] ) ----------------
__global__ __launch_bounds__(512) void pq_gemm(
        const float* __restrict__ x, const ushort* __restrict__ Wp,
        const float* __restrict__ bias1, const float* __restrict__ T12,
        const int* __restrict__ batch, ushort* __restrict__ out) {
    const int tid = threadIdx.x;
    const int w = tid >> 6, l = tid & 63, lr = l & 15, lg = l >> 4;
    const int node = blockIdx.x * 128 + w * 16 + lr;

    short8 xa[2];
#pragma unroll
    for (int ks = 0; ks < 2; ++ks) {
        const float4* bp = reinterpret_cast<const float4*>(x + (long)node * 64 + ks * 32 + lg * 8);
        float4 f0 = bp[0], f1 = bp[1];
        union { short8 s; unsigned int u[4]; } t;
        t.u[0] = cvt_pk_bf16(f0.x, f0.y);
        t.u[1] = cvt_pk_bf16(f0.z, f0.w);
        t.u[2] = cvt_pk_bf16(f1.x, f1.y);
        t.u[3] = cvt_pk_bf16(f1.z, f1.w);
        xa[ks] = t.s;
    }
    f32x4 acc[16];
#pragma unroll
    for (int t = 0; t < 16; ++t)
#pragma unroll
        for (int i = 0; i < 4; ++i)
            acc[t][i] = (t < 8) ? bias1[t * 16 + lg * 4 + i] : 0.f;
#pragma unroll
    for (int ks = 0; ks < 2; ++ks)
#pragma unroll
        for (int t = 0; t < 16; ++t) {
            short8 wf = *reinterpret_cast<const short8*>(Wp + (((ks * 4 + lg) * 256) + t * 16 + lr) * 8);
            acc[t] = __builtin_amdgcn_mfma_f32_16x16x32_bf16(wf, xa[ks], acc[t], 0, 0, 0);
        }
    if (T12) {
        const float* tp = T12 + (long)batch[node] * 256;
#pragma unroll
        for (int t = 0; t < 16; ++t)
#pragma unroll
            for (int i = 0; i < 4; ++i)
                acc[t][i] += tp[t * 16 + lg * 4 + i];
    }
#pragma unroll
    for (int t = 0; t < 16; ++t) {
        uint2 v;
        v.x = cvt_pk_bf16(acc[t][0], acc[t][1]);
        v.y = cvt_pk_bf16(acc[t][2], acc[t][3]);
        *reinterpret_cast<uint2*>(out + (long)node * 256 + t * 16 + lg * 4) = v;
    }
}

// ---------------- global edge pass (CSR): reg-accumulated pooling ----------------
__global__ __launch_bounds__(256) void global_edge(
        const ushort* __restrict__ PQ, const int* __restrict__ csr,
        const int* __restrict__ offs, const float* __restrict__ e,
        const int* __restrict__ batch,
        float* __restrict__ hidpart, float* __restrict__ esumpart) {
    const int tid = threadIdx.x;
    const int w = tid >> 6, l = tid & 63;
    const int wid = blockIdx.x * 4 + w;
    const int node0 = wid * NPW;
    const int slot = wid & (NS - 1);

    const int offv = offs[node0 + ((l < 17) ? l : 16)];
    const float evv = e[node0 + (l & 15)];
    const int bv = batch[node0 + (l & 15)];

    float accp0 = 0.f, accp1 = 0.f, eacc = 0.f;
    int curb = __shfl(bv, 0, 64);

    for (int n = 0; n < NPW; ++n) {
        const int off = __shfl(offv, n, 64);
        const int cnt = __shfl(offv, n + 1, 64) - off;
        const int bb  = __shfl(bv, n, 64);
        const float ev = __shfl(evv, n, 64);
        if (bb != curb) {
            float* hp = hidpart + (long)slot * (BB * 128) + curb * 128;
            atomicAdd(hp + 2 * l, accp0);
            atomicAdd(hp + 2 * l + 1, accp1);
            if (l == 0) atomicAdd(&esumpart[slot * BB + curb], eacc);
            accp0 = accp1 = eacc = 0.f;
            curb = bb;
        }
        if (cnt <= 0) continue;
        const unsigned int pdu = *reinterpret_cast<const unsigned int*>(PQ + (long)(node0 + n) * 256 + 2 * l);
        const float p0 = __uint_as_float(pdu << 16);
        const float p1 = __uint_as_float(pdu & 0xFFFF0000u);
        float h0 = 0.f, h1 = 0.f;
        for (int g0 = 0; g0 < cnt; g0 += 64) {
            int m = cnt - g0; if (m > 64) m = 64;
            const int srcv = csr[off + g0 + ((l < m) ? l : (m - 1))];
            for (int jj = 0; jj < m; jj += 8) {
                unsigned int qv[8];
#pragma unroll
                for (int k = 0; k < 8; ++k) {
                    int kk = jj + k; if (kk > m - 1) kk = m - 1;
                    const int s = __shfl(srcv, kk, 64);
                    qv[k] = *reinterpret_cast<const unsigned int*>(PQ + (long)s * 256 + 128 + 2 * l);
                }
#pragma unroll
                for (int k = 0; k < 8; ++k) {
                    const float q0 = __uint_as_float(qv[k] << 16);
                    const float q1 = __uint_as_float(qv[k] & 0xFFFF0000u);
                    const float r0 = fmaxf(p0 + q0, 0.f);
                    const float r1 = fmaxf(p1 + q1, 0.f);
                    if (jj + k < m) { h0 += r0; h1 += r1; }
                }
            }
        }
        accp0 += ev * h0; accp1 += ev * h1; eacc += ev * (float)cnt;
    }
    {
        float* hp = hidpart + (long)slot * (BB * 128) + curb * 128;
        atomicAdd(hp + 2 * l, accp0);
        atomicAdd(hp + 2 * l + 1, accp1);
        if (l == 0) atomicAdd(&esumpart[slot * BB + curb], eacc);
    }
}

// ---------------- fused: hidsum reduce -> pooled (LDS only) -> T12 ----------------
__global__ __launch_bounds__(256) void pooled_t12_kernel(
        const float* __restrict__ hidpart, const float* __restrict__ esumpart,
        const float* __restrict__ gW2, const float* __restrict__ gb2,
        const float* __restrict__ lW1, float* __restrict__ T12) {
    __shared__ float hs[128];
    __shared__ float qacc[4][64];
    __shared__ float pb[64];
    __shared__ float esv;
    const int b = blockIdx.x, tid = threadIdx.x;
    if (tid < 128) {
        float s = 0.f;
        for (int sl = 0; sl < NS; ++sl) s += hidpart[(long)sl * (BB * 128) + b * 128 + tid];
        hs[tid] = s;
    } else if (tid == 128) {
        float s = 0.f;
        for (int sl = 0; sl < NS; ++sl) s += esumpart[sl * BB + b];
        esv = s;
    }
    __syncthreads();
    {
        int col = tid & 63, qr = tid >> 6;
        float a = 0.f;
        for (int k = qr * 32; k < qr * 32 + 32; ++k) a += hs[k] * gW2[k * 64 + col];
        qacc[qr][col] = a;
    }
    __syncthreads();
    if (tid < 64) pb[tid] = qacc[0][tid] + qacc[1][tid] + qacc[2][tid] + qacc[3][tid] + esv * gb2[tid];
    __syncthreads();
    const float* col = (tid < 128) ? (lW1 + 64 * 128 + tid) : (lW1 + 192 * 128 + (tid - 128));
    float acc = 0.f;
    for (int k = 0; k < 64; ++k) acc += pb[k] * col[k * 128];
    T12[b * 256 + tid] = acc;
}

// ---------------- local edge pass (CSR): out[n] = sum_src relu(PL[n]+QL[src])·w2 + cnt*b2 ----------------
__global__ __launch_bounds__(256) void local_edge(
        const ushort* __restrict__ PQL, const int* __restrict__ csr,
        const int* __restrict__ offs, const float* __restrict__ lW2,
        const float* __restrict__ lb2, float* __restrict__ out) {
    const int tid = threadIdx.x;
    const int w = tid >> 6, l = tid & 63;
    const int wid = blockIdx.x * 4 + w;
    const int node0 = wid * NPW;
    const int offv = offs[node0 + ((l < 17) ? l : 16)];
    const float w20 = lW2[2 * l], w21 = lW2[2 * l + 1];
    const float b2v = lb2[0];

    for (int n = 0; n < NPW; ++n) {
        const int off = __shfl(offv, n, 64);
        const int cnt = __shfl(offv, n + 1, 64) - off;
        float dacc = 0.f;
        if (cnt > 0) {
            const unsigned int pdu = *reinterpret_cast<const unsigned int*>(PQL + (long)(node0 + n) * 256 + 2 * l);
            const float p0 = __uint_as_float(pdu << 16);
            const float p1 = __uint_as_float(pdu & 0xFFFF0000u);
            for (int g0 = 0; g0 < cnt; g0 += 64) {
                int m = cnt - g0; if (m > 64) m = 64;
                const int srcv = csr[off + g0 + ((l < m) ? l : (m - 1))];
                for (int jj = 0; jj < m; jj += 8) {
                    unsigned int qv[8];
#pragma unroll
                    for (int k = 0; k < 8; ++k) {
                        int kk = jj + k; if (kk > m - 1) kk = m - 1;
                        const int s = __shfl(srcv, kk, 64);
                        qv[k] = *reinterpret_cast<const unsigned int*>(PQL + (long)s * 256 + 128 + 2 * l);
                    }
#pragma unroll
                    for (int k = 0; k < 8; ++k) {
                        const float q0 = __uint_as_float(qv[k] << 16);
                        const float q1 = __uint_as_float(qv[k] & 0xFFFF0000u);
                        const float t0 = fmaxf(p0 + q0, 0.f) * w20 + fmaxf(p1 + q1, 0.f) * w21;
                        if (jj + k < m) dacc += t0;
                    }
                }
            }
            dacc += __shfl_xor(dacc, 1, 64);
            dacc += __shfl_xor(dacc, 2, 64);
            dacc += __shfl_xor(dacc, 4, 64);
            dacc += __shfl_xor(dacc, 8, 64);
            dacc += __shfl_xor(dacc, 16, 64);
            dacc += __shfl_xor(dacc, 32, 64);
        }
        if (l == 0) out[node0 + n] = dacc + (float)cnt * b2v;
    }
}

extern "C" void kernel_launch(void* const* d_in, const int* in_sizes, int n_in,
                              void* d_out, int out_size, void* d_ws, size_t ws_size,
                              hipStream_t stream) {
    const float* x   = (const float*)d_in[0];
    const float* e   = (const float*)d_in[1];
    const int*   ei  = (const int*)d_in[2];
    const int*   bat = (const int*)d_in[3];
    const float* gW1 = (const float*)d_in[4];
    const float* gb1 = (const float*)d_in[5];
    const float* gW2 = (const float*)d_in[6];
    const float* gb2 = (const float*)d_in[7];
    const float* lW1 = (const float*)d_in[8];
    const float* lb1 = (const float*)d_in[9];
    const float* lW2 = (const float*)d_in[10];
    const float* lb2 = (const float*)d_in[11];

    char* ws = (char*)d_ws;
    ushort* W1p     = (ushort*)(ws);                     //    32768 B
    ushort* L1p     = (ushort*)(ws + 32768);             //    32768 B
    float*  T12     = (float*)(ws + 65536);              //    65536 B
    float*  esumpart= (float*)(ws + 131072);             //     8192 B
    float*  hidpart = (float*)(ws + 139264);             //  1048576 B
    int*    counts  = (int*)(ws + 1187840);              //   204800 B
    int*    offs    = (int*)(ws + 1392640);              //   204816 B (51201 ints)
    int*    cursor  = (int*)(ws + 1597456);              //   204800 B
    int*    bcur    = (int*)(ws + 1802256);              //    32768 B (512 line-padded)
    int*    csum    = (int*)(ws + 1835024);              //     1024 B (NCHUNK ints, padded)
    int*    cbase   = (int*)(ws + 1836048);              //     1024 B
    int*    csr     = (int*)(ws + 1837072);              //  3276800 B
    ushort* PQ      = (ushort*)(ws + 5113872);           // 26214400 B (btmp overlays; reused for PQL)
    int2*   btmp    = (int2*)PQ;                         // 6553600 B, consumed before pq_gemm

    hipMemsetAsync(counts, 0, 204800, stream);
    hipMemsetAsync(esumpart, 0, 8192 + 1048576, stream);           // esumpart + hidpart
    hipMemsetAsync(d_out, 0, (size_t)out_size * sizeof(float), stream);

    prep_weights<<<1, 512, 0, stream>>>(gW1, lW1, W1p, L1p);
    hist_kernel<<<EE / 256, 256, 0, stream>>>(ei, counts);
    chunk_sum_kernel<<<NCHUNK, 256, 0, stream>>>(counts, csum);
    chunk_scan_kernel<<<1, 256, 0, stream>>>(csum, cbase);
    offs_kernel<<<NCHUNK, 256, 0, stream>>>(counts, cbase, offs, cursor, bcur);
    bucketA_kernel<<<EE / 256, 256, 0, stream>>>(ei, bcur, btmp);
    bucketB_kernel<<<NBUCK, 256, 0, stream>>>(btmp, offs, cursor, csr);

    pq_gemm<<<NN / 128, 512, 0, stream>>>(x, W1p, gb1, nullptr, bat, PQ);
    global_edge<<<NN / (4 * NPW), 256, 0, stream>>>(PQ, csr, offs, e, bat, hidpart, esumpart);
    pooled_t12_kernel<<<BB, 256, 0, stream>>>(hidpart, esumpart, gW2, gb2, lW1, T12);
    pq_gemm<<<NN / 128, 512, 0, stream>>>(x, L1p, lb1, T12, bat, PQ);   // -> PQL
    local_edge<<<NN / (4 * NPW), 256, 0, stream>>>(PQ, csr, offs, lW2, lb2, (float*)d_out);
}

// Round 7
// 273.845 us; speedup vs baseline: 1.3213x; 1.0044x over previous
//
#include <hip/hip_runtime.h>
#include <hip/hip_bf16.h>

#define NN 51200
#define EE 819200
#define BB 64
#define NS 32
#define NPW 8       // nodes per wave in edge passes
#define NBUCK 512   // dst-range buckets for scatter
#define NPB 100     // nodes per bucket = NN/NBUCK
#define NCHUNK 200  // scan chunks = NN/256

typedef __attribute__((ext_vector_type(8))) short short8;
typedef __attribute__((ext_vector_type(4))) float f32x4;

__device__ __forceinline__ ushort f2bf(float f) {
    unsigned int u = __float_as_uint(f);
    unsigned int r = (u + 0x7FFFu + ((u >> 16) & 1u)) >> 16;   // RNE, finite inputs
    return (ushort)r;
}
__device__ __forceinline__ unsigned int cvt_pk_bf16(float lo, float hi) {
    unsigned int r;
    asm("v_cvt_pk_bf16_f32 %0, %1, %2" : "=v"(r) : "v"(lo), "v"(hi));
    return r;
}

// ---------------- weight prep ----------------
__global__ void prep_weights(const float* __restrict__ gW1, const float* __restrict__ lW1,
                             ushort* __restrict__ W1p, ushort* __restrict__ L1p) {
    int tid = threadIdx.x;
    for (int idx = tid; idx < 64 * 256; idx += 512) {
        int i = idx & 7, c = (idx >> 3) & 255, q = idx >> 11;
        int k = (q >> 2) * 32 + (q & 3) * 8 + i;
        W1p[idx] = f2bf(c < 128 ? gW1[k * 128 + c] : gW1[(64 + k) * 128 + (c - 128)]);
        L1p[idx] = f2bf(c < 128 ? lW1[k * 128 + c] : lW1[(128 + k) * 128 + (c - 128)]);
    }
}

// ---------------- CSR build ----------------
__global__ void hist_kernel(const int* __restrict__ eidx, int* __restrict__ cnt) {
    int i = blockIdx.x * 256 + threadIdx.x;
    atomicAdd(&cnt[eidx[EE + i]], 1);
}

__global__ __launch_bounds__(256) void chunk_sum_kernel(const int* __restrict__ cnt,
                                                        int* __restrict__ csum) {
    __shared__ int red[4];
    const int t = threadIdx.x;
    int v = cnt[blockIdx.x * 256 + t];
#pragma unroll
    for (int m = 1; m < 64; m <<= 1) v += __shfl_xor(v, m, 64);
    if ((t & 63) == 0) red[t >> 6] = v;
    __syncthreads();
    if (t == 0) csum[blockIdx.x] = red[0] + red[1] + red[2] + red[3];
}

__global__ __launch_bounds__(256) void chunk_scan_kernel(const int* __restrict__ csum,
                                                         int* __restrict__ cbase) {
    __shared__ int s[256];
    const int t = threadIdx.x;
    int v = (t < NCHUNK) ? csum[t] : 0;
    s[t] = v;
    __syncthreads();
    for (int o = 1; o < 256; o <<= 1) {
        int u = (t >= o) ? s[t - o] : 0;
        __syncthreads();
        s[t] += u;
        __syncthreads();
    }
    if (t < NCHUNK) cbase[t] = s[t] - v;
}

__global__ __launch_bounds__(256) void offs_kernel(const int* __restrict__ cnt,
                                                   const int* __restrict__ cbase,
                                                   int* __restrict__ offs,
                                                   int* __restrict__ cursor,
                                                   int* __restrict__ bcur) {
    __shared__ int s[256];
    const int t = threadIdx.x;
    const int node = blockIdx.x * 256 + t;
    const int c = cnt[node];
    s[t] = c;
    __syncthreads();
    for (int o = 1; o < 256; o <<= 1) {
        int u = (t >= o) ? s[t - o] : 0;
        __syncthreads();
        s[t] += u;
        __syncthreads();
    }
    const int run = cbase[blockIdx.x] + s[t] - c;   // exclusive prefix
    offs[node] = run;
    cursor[node] = run;
    if (node % NPB == 0) bcur[(node / NPB) * 16] = run;
    if (node == NN - 1) offs[NN] = EE;
}

__global__ void bucketA_kernel(const int* __restrict__ eidx, int* __restrict__ bcur,
                               int2* __restrict__ btmp) {
    int i = blockIdx.x * 256 + threadIdx.x;
    int d = eidx[EE + i], s = eidx[i];
    int pos = atomicAdd(&bcur[(d / NPB) * 16], 1);
    btmp[pos] = make_int2(s, d);
}

__global__ __launch_bounds__(256) void bucketB_kernel(const int2* __restrict__ btmp,
                                                      const int* __restrict__ offs,
                                                      int* __restrict__ cursor,
                                                      int* __restrict__ csr) {
    const int bkt = blockIdx.x;
    const int begin = offs[bkt * NPB], end = offs[(bkt + 1) * NPB];
    for (int i = begin + threadIdx.x; i < end; i += 256) {
        int2 p = btmp[i];
        int pos = atomicAdd(&cursor[p.y], 1);
        csr[pos] = p.x;
    }
}

// ---------------- node-table GEMM: out[n][0:256] = bf16( x[n]@Wcat + bias_fold + T12[batch[n]] ) ----------------
__global__ __launch_bounds__(512) void pq_gemm(
        const float* __restrict__ x, const ushort* __restrict__ Wp,
        const float* __restrict__ bias1, const float* __restrict__ T12,
        const int* __restrict__ batch, ushort* __restrict__ out) {
    const int tid = threadIdx.x;
    const int w = tid >> 6, l = tid & 63, lr = l & 15, lg = l >> 4;
    const int node = blockIdx.x * 128 + w * 16 + lr;

    short8 xa[2];
#pragma unroll
    for (int ks = 0; ks < 2; ++ks) {
        const float4* bp = reinterpret_cast<const float4*>(x + (long)node * 64 + ks * 32 + lg * 8);
        float4 f0 = bp[0], f1 = bp[1];
        union { short8 s; unsigned int u[4]; } t;
        t.u[0] = cvt_pk_bf16(f0.x, f0.y);
        t.u[1] = cvt_pk_bf16(f0.z, f0.w);
        t.u[2] = cvt_pk_bf16(f1.x, f1.y);
        t.u[3] = cvt_pk_bf16(f1.z, f1.w);
        xa[ks] = t.s;
    }
    f32x4 acc[16];
#pragma unroll
    for (int t = 0; t < 16; ++t)
#pragma unroll
        for (int i = 0; i < 4; ++i)
            acc[t][i] = (t < 8) ? bias1[t * 16 + lg * 4 + i] : 0.f;
#pragma unroll
    for (int ks = 0; ks < 2; ++ks)
#pragma unroll
        for (int t = 0; t < 16; ++t) {
            short8 wf = *reinterpret_cast<const short8*>(Wp + (((ks * 4 + lg) * 256) + t * 16 + lr) * 8);
            acc[t] = __builtin_amdgcn_mfma_f32_16x16x32_bf16(wf, xa[ks], acc[t], 0, 0, 0);
        }
    if (T12) {
        const float* tp = T12 + (long)batch[node] * 256;
#pragma unroll
        for (int t = 0; t < 16; ++t)
#pragma unroll
            for (int i = 0; i < 4; ++i)
                acc[t][i] += tp[t * 16 + lg * 4 + i];
    }
#pragma unroll
    for (int t = 0; t < 16; ++t) {
        uint2 v;
        v.x = cvt_pk_bf16(acc[t][0], acc[t][1]);
        v.y = cvt_pk_bf16(acc[t][2], acc[t][3]);
        *reinterpret_cast<uint2*>(out + (long)node * 256 + t * 16 + lg * 4) = v;
    }
}

// ---------------- global edge pass (CSR, 16 lanes/edge, dwordx4 gathers) ----------------
// lane l: group q=l>>4 (edge within quad), channels c16*8..c16*8+7 (c16=l&15)
__global__ __launch_bounds__(256) void global_edge(
        const ushort* __restrict__ PQ, const int* __restrict__ csr,
        const int* __restrict__ offs, const float* __restrict__ e,
        const int* __restrict__ batch,
        float* __restrict__ hidpart, float* __restrict__ esumpart) {
    const int tid = threadIdx.x;
    const int w = tid >> 6, l = tid & 63, q = l >> 4, c16 = l & 15;
    const int wid = blockIdx.x * 4 + w;
    const int node0 = wid * NPW;
    const int slot = wid & (NS - 1);

    const int offv = offs[node0 + ((l < NPW + 1) ? l : NPW)];
    const float evv = e[node0 + (l & (NPW - 1))];
    const int bv = batch[node0 + (l & (NPW - 1))];

    float accp[8];
#pragma unroll
    for (int j = 0; j < 8; ++j) accp[j] = 0.f;
    float eacc = 0.f;
    int curb = __shfl(bv, 0, 64);

    for (int n = 0; n < NPW; ++n) {
        const int off = __shfl(offv, n, 64);
        const int cnt = __shfl(offv, n + 1, 64) - off;
        const int bb  = __shfl(bv, n, 64);
        const float ev = __shfl(evv, n, 64);
        if (bb != curb) {   // flush (wave-uniform): cross-group reduce, then atomics
#pragma unroll
            for (int j = 0; j < 8; ++j) {
                accp[j] += __shfl_xor(accp[j], 16, 64);
                accp[j] += __shfl_xor(accp[j], 32, 64);
            }
            float* hp = hidpart + (long)slot * (BB * 128) + curb * 128 + c16 * 8;
            if (q == 0) {
#pragma unroll
                for (int j = 0; j < 8; ++j) atomicAdd(hp + j, accp[j]);
            }
            if (l == 0) atomicAdd(&esumpart[slot * BB + curb], eacc);
#pragma unroll
            for (int j = 0; j < 8; ++j) accp[j] = 0.f;
            eacc = 0.f;
            curb = bb;
        }
        if (cnt <= 0) continue;
        // P row for this node (16 B/lane, same across groups)
        uint4 pdu = *reinterpret_cast<const uint4*>(PQ + (long)(node0 + n) * 256 + c16 * 8);
        float pv[8];
        pv[0] = __uint_as_float(pdu.x << 16); pv[1] = __uint_as_float(pdu.x & 0xFFFF0000u);
        pv[2] = __uint_as_float(pdu.y << 16); pv[3] = __uint_as_float(pdu.y & 0xFFFF0000u);
        pv[4] = __uint_as_float(pdu.z << 16); pv[5] = __uint_as_float(pdu.z & 0xFFFF0000u);
        pv[6] = __uint_as_float(pdu.w << 16); pv[7] = __uint_as_float(pdu.w & 0xFFFF0000u);
        float h[8];
#pragma unroll
        for (int j = 0; j < 8; ++j) h[j] = 0.f;
        for (int g0 = 0; g0 < cnt; g0 += 64) {
            const int m = (cnt - g0 < 64) ? (cnt - g0) : 64;
            const int srcv = csr[off + g0 + ((l < m) ? l : (m - 1))];
            const int s0 = __shfl(srcv, (q < m) ? q : (m - 1), 64);
            uint4 qv = *reinterpret_cast<const uint4*>(PQ + (long)s0 * 256 + 128 + c16 * 8);
            for (int jj = 0; jj < m; jj += 4) {
                uint4 qn = qv;
                if (jj + 4 < m) {     // prefetch next quad
                    const int si = jj + 4 + q;
                    const int sn = __shfl(srcv, (si < m) ? si : (m - 1), 64);
                    qn = *reinterpret_cast<const uint4*>(PQ + (long)sn * 256 + 128 + c16 * 8);
                }
                if (jj + q < m) {
                    h[0] += fmaxf(pv[0] + __uint_as_float(qv.x << 16), 0.f);
                    h[1] += fmaxf(pv[1] + __uint_as_float(qv.x & 0xFFFF0000u), 0.f);
                    h[2] += fmaxf(pv[2] + __uint_as_float(qv.y << 16), 0.f);
                    h[3] += fmaxf(pv[3] + __uint_as_float(qv.y & 0xFFFF0000u), 0.f);
                    h[4] += fmaxf(pv[4] + __uint_as_float(qv.z << 16), 0.f);
                    h[5] += fmaxf(pv[5] + __uint_as_float(qv.z & 0xFFFF0000u), 0.f);
                    h[6] += fmaxf(pv[6] + __uint_as_float(qv.w << 16), 0.f);
                    h[7] += fmaxf(pv[7] + __uint_as_float(qv.w & 0xFFFF0000u), 0.f);
                }
                qv = qn;
            }
        }
#pragma unroll
        for (int j = 0; j < 8; ++j) accp[j] += ev * h[j];   // group partial
        eacc += ev * (float)cnt;
    }
    {   // final flush
#pragma unroll
        for (int j = 0; j < 8; ++j) {
            accp[j] += __shfl_xor(accp[j], 16, 64);
            accp[j] += __shfl_xor(accp[j], 32, 64);
        }
        float* hp = hidpart + (long)slot * (BB * 128) + curb * 128 + c16 * 8;
        if (q == 0) {
#pragma unroll
            for (int j = 0; j < 8; ++j) atomicAdd(hp + j, accp[j]);
        }
        if (l == 0) atomicAdd(&esumpart[slot * BB + curb], eacc);
    }
}

// ---------------- fused: hidsum reduce -> pooled (LDS only) -> T12 ----------------
__global__ __launch_bounds__(256) void pooled_t12_kernel(
        const float* __restrict__ hidpart, const float* __restrict__ esumpart,
        const float* __restrict__ gW2, const float* __restrict__ gb2,
        const float* __restrict__ lW1, float* __restrict__ T12) {
    __shared__ float hs[128];
    __shared__ float qacc[4][64];
    __shared__ float pb[64];
    __shared__ float esv;
    const int b = blockIdx.x, tid = threadIdx.x;
    if (tid < 128) {
        float s = 0.f;
        for (int sl = 0; sl < NS; ++sl) s += hidpart[(long)sl * (BB * 128) + b * 128 + tid];
        hs[tid] = s;
    } else if (tid == 128) {
        float s = 0.f;
        for (int sl = 0; sl < NS; ++sl) s += esumpart[sl * BB + b];
        esv = s;
    }
    __syncthreads();
    {
        int col = tid & 63, qr = tid >> 6;
        float a = 0.f;
        for (int k = qr * 32; k < qr * 32 + 32; ++k) a += hs[k] * gW2[k * 64 + col];
        qacc[qr][col] = a;
    }
    __syncthreads();
    if (tid < 64) pb[tid] = qacc[0][tid] + qacc[1][tid] + qacc[2][tid] + qacc[3][tid] + esv * gb2[tid];
    __syncthreads();
    const float* col = (tid < 128) ? (lW1 + 64 * 128 + tid) : (lW1 + 192 * 128 + (tid - 128));
    float acc = 0.f;
    for (int k = 0; k < 64; ++k) acc += pb[k] * col[k * 128];
    T12[b * 256 + tid] = acc;
}

// ---------------- local edge pass (CSR, 16 lanes/edge, dwordx4 gathers) ----------------
__global__ __launch_bounds__(256) void local_edge(
        const ushort* __restrict__ PQL, const int* __restrict__ csr,
        const int* __restrict__ offs, const float* __restrict__ lW2,
        const float* __restrict__ lb2, float* __restrict__ out) {
    const int tid = threadIdx.x;
    const int w = tid >> 6, l = tid & 63, q = l >> 4, c16 = l & 15;
    const int wid = blockIdx.x * 4 + w;
    const int node0 = wid * NPW;
    const int offv = offs[node0 + ((l < NPW + 1) ? l : NPW)];
    float w2r[8];
#pragma unroll
    for (int j = 0; j < 8; ++j) w2r[j] = lW2[c16 * 8 + j];
    const float b2v = lb2[0];

    for (int n = 0; n < NPW; ++n) {
        const int off = __shfl(offv, n, 64);
        const int cnt = __shfl(offv, n + 1, 64) - off;
        float dacc = 0.f;
        if (cnt > 0) {
            uint4 pdu = *reinterpret_cast<const uint4*>(PQL + (long)(node0 + n) * 256 + c16 * 8);
            float pv[8];
            pv[0] = __uint_as_float(pdu.x << 16); pv[1] = __uint_as_float(pdu.x & 0xFFFF0000u);
            pv[2] = __uint_as_float(pdu.y << 16); pv[3] = __uint_as_float(pdu.y & 0xFFFF0000u);
            pv[4] = __uint_as_float(pdu.z << 16); pv[5] = __uint_as_float(pdu.z & 0xFFFF0000u);
            pv[6] = __uint_as_float(pdu.w << 16); pv[7] = __uint_as_float(pdu.w & 0xFFFF0000u);
            for (int g0 = 0; g0 < cnt; g0 += 64) {
                const int m = (cnt - g0 < 64) ? (cnt - g0) : 64;
                const int srcv = csr[off + g0 + ((l < m) ? l : (m - 1))];
                const int s0 = __shfl(srcv, (q < m) ? q : (m - 1), 64);
                uint4 qv = *reinterpret_cast<const uint4*>(PQL + (long)s0 * 256 + 128 + c16 * 8);
                for (int jj = 0; jj < m; jj += 4) {
                    uint4 qn = qv;
                    if (jj + 4 < m) {
                        const int si = jj + 4 + q;
                        const int sn = __shfl(srcv, (si < m) ? si : (m - 1), 64);
                        qn = *reinterpret_cast<const uint4*>(PQL + (long)sn * 256 + 128 + c16 * 8);
                    }
                    if (jj + q < m) {
                        dacc += fmaxf(pv[0] + __uint_as_float(qv.x << 16), 0.f) * w2r[0]
                              + fmaxf(pv[1] + __uint_as_float(qv.x & 0xFFFF0000u), 0.f) * w2r[1]
                              + fmaxf(pv[2] + __uint_as_float(qv.y << 16), 0.f) * w2r[2]
                              + fmaxf(pv[3] + __uint_as_float(qv.y & 0xFFFF0000u), 0.f) * w2r[3]
                              + fmaxf(pv[4] + __uint_as_float(qv.z << 16), 0.f) * w2r[4]
                              + fmaxf(pv[5] + __uint_as_float(qv.z & 0xFFFF0000u), 0.f) * w2r[5]
                              + fmaxf(pv[6] + __uint_as_float(qv.w << 16), 0.f) * w2r[6]
                              + fmaxf(pv[7] + __uint_as_float(qv.w & 0xFFFF0000u), 0.f) * w2r[7];
                    }
                    qv = qn;
                }
            }
            dacc += __shfl_xor(dacc, 1, 64);
            dacc += __shfl_xor(dacc, 2, 64);
            dacc += __shfl_xor(dacc, 4, 64);
            dacc += __shfl_xor(dacc, 8, 64);
            dacc += __shfl_xor(dacc, 16, 64);
            dacc += __shfl_xor(dacc, 32, 64);
        }
        if (l == 0) out[node0 + n] = dacc + (float)cnt * b2v;
    }
}

extern "C" void kernel_launch(void* const* d_in, const int* in_sizes, int n_in,
                              void* d_out, int out_size, void* d_ws, size_t ws_size,
                              hipStream_t stream) {
    const float* x   = (const float*)d_in[0];
    const float* e   = (const float*)d_in[1];
    const int*   ei  = (const int*)d_in[2];
    const int*   bat = (const int*)d_in[3];
    const float* gW1 = (const float*)d_in[4];
    const float* gb1 = (const float*)d_in[5];
    const float* gW2 = (const float*)d_in[6];
    const float* gb2 = (const float*)d_in[7];
    const float* lW1 = (const float*)d_in[8];
    const float* lb1 = (const float*)d_in[9];
    const float* lW2 = (const float*)d_in[10];
    const float* lb2 = (const float*)d_in[11];

    char* ws = (char*)d_ws;
    ushort* W1p     = (ushort*)(ws);                     //    32768 B
    ushort* L1p     = (ushort*)(ws + 32768);             //    32768 B
    float*  T12     = (float*)(ws + 65536);              //    65536 B
    float*  esumpart= (float*)(ws + 131072);             //     8192 B
    float*  hidpart = (float*)(ws + 139264);             //  1048576 B
    int*    counts  = (int*)(ws + 1187840);              //   204800 B
    int*    offs    = (int*)(ws + 1392640);              //   204816 B (51201 ints)
    int*    cursor  = (int*)(ws + 1597456);              //   204800 B
    int*    bcur    = (int*)(ws + 1802256);              //    32768 B (512 line-padded)
    int*    csum    = (int*)(ws + 1835024);              //     1024 B
    int*    cbase   = (int*)(ws + 1836048);              //     1024 B
    int*    csr     = (int*)(ws + 1837072);              //  3276800 B
    ushort* PQ      = (ushort*)(ws + 5113872);           // 26214400 B (btmp overlays; reused for PQL)
    int2*   btmp    = (int2*)PQ;                         // 6553600 B, consumed before pq_gemm

    hipMemsetAsync(counts, 0, 204800, stream);
    hipMemsetAsync(esumpart, 0, 8192 + 1048576, stream);           // esumpart + hidpart
    hipMemsetAsync(d_out, 0, (size_t)out_size * sizeof(float), stream);

    prep_weights<<<1, 512, 0, stream>>>(gW1, lW1, W1p, L1p);
    hist_kernel<<<EE / 256, 256, 0, stream>>>(ei, counts);
    chunk_sum_kernel<<<NCHUNK, 256, 0, stream>>>(counts, csum);
    chunk_scan_kernel<<<1, 256, 0, stream>>>(csum, cbase);
    offs_kernel<<<NCHUNK, 256, 0, stream>>>(counts, cbase, offs, cursor, bcur);
    bucketA_kernel<<<EE / 256, 256, 0, stream>>>(ei, bcur, btmp);
    bucketB_kernel<<<NBUCK, 256, 0, stream>>>(btmp, offs, cursor, csr);

    pq_gemm<<<NN / 128, 512, 0, stream>>>(x, W1p, gb1, nullptr, bat, PQ);
    global_edge<<<NN / (4 * NPW), 256, 0, stream>>>(PQ, csr, offs, e, bat, hidpart, esumpart);
    pooled_t12_kernel<<<BB, 256, 0, stream>>>(hidpart, esumpart, gW2, gb2, lW1, T12);
    pq_gemm<<<NN / 128, 512, 0, stream>>>(x, L1p, lb1, T12, bat, PQ);   // -> PQL
    local_edge<<<NN / (4 * NPW), 256, 0, stream>>>(PQ, csr, offs, lW2, lb2, (float*)d_out);
}

// Round 8
// 258.694 us; speedup vs baseline: 1.3987x; 1.0586x over previous
//
#include <hip/hip_runtime.h>
#include <hip/hip_bf16.h>

#define NN 51200
#define EE 819200
#define BB 64
#define NS 32
#define NPW 4       // nodes per wave in edge passes
#define NBUCK 512   // dst-range buckets for scatter
#define NPB 100     // nodes per bucket = NN/NBUCK
#define CAP 4096    // bucket capacity (mean 1600, std ~40)

typedef __attribute__((ext_vector_type(8))) short short8;
typedef __attribute__((ext_vector_type(4))) float f32x4;

__device__ __forceinline__ ushort f2bf(float f) {
    unsigned int u = __float_as_uint(f);
    unsigned int r = (u + 0x7FFFu + ((u >> 16) & 1u)) >> 16;   // RNE, finite inputs
    return (ushort)r;
}
__device__ __forceinline__ unsigned int cvt_pk_bf16(float lo, float hi) {
    unsigned int r;
    asm("v_cvt_pk_bf16_f32 %0, %1, %2" : "=v"(r) : "v"(lo), "v"(hi));
    return r;
}
__device__ __forceinline__ uint4 ldQ(const ushort* __restrict__ PQ, int s, int c16) {
    return *reinterpret_cast<const uint4*>(PQ + (long)s * 256 + 128 + c16 * 8);
}
__device__ __forceinline__ void unpack8(uint4 v, float* p) {
    p[0] = __uint_as_float(v.x << 16); p[1] = __uint_as_float(v.x & 0xFFFF0000u);
    p[2] = __uint_as_float(v.y << 16); p[3] = __uint_as_float(v.y & 0xFFFF0000u);
    p[4] = __uint_as_float(v.z << 16); p[5] = __uint_as_float(v.z & 0xFFFF0000u);
    p[6] = __uint_as_float(v.w << 16); p[7] = __uint_as_float(v.w & 0xFFFF0000u);
}
__device__ __forceinline__ void acc_relu8(const float* pv, uint4 v, float* h) {
    h[0] += fmaxf(pv[0] + __uint_as_float(v.x << 16), 0.f);
    h[1] += fmaxf(pv[1] + __uint_as_float(v.x & 0xFFFF0000u), 0.f);
    h[2] += fmaxf(pv[2] + __uint_as_float(v.y << 16), 0.f);
    h[3] += fmaxf(pv[3] + __uint_as_float(v.y & 0xFFFF0000u), 0.f);
    h[4] += fmaxf(pv[4] + __uint_as_float(v.z << 16), 0.f);
    h[5] += fmaxf(pv[5] + __uint_as_float(v.z & 0xFFFF0000u), 0.f);
    h[6] += fmaxf(pv[6] + __uint_as_float(v.w << 16), 0.f);
    h[7] += fmaxf(pv[7] + __uint_as_float(v.w & 0xFFFF0000u), 0.f);
}
__device__ __forceinline__ float dot_relu8(const float* pv, uint4 v, const float* w) {
    return fmaxf(pv[0] + __uint_as_float(v.x << 16), 0.f) * w[0]
         + fmaxf(pv[1] + __uint_as_float(v.x & 0xFFFF0000u), 0.f) * w[1]
         + fmaxf(pv[2] + __uint_as_float(v.y << 16), 0.f) * w[2]
         + fmaxf(pv[3] + __uint_as_float(v.y & 0xFFFF0000u), 0.f) * w[3]
         + fmaxf(pv[4] + __uint_as_float(v.z << 16), 0.f) * w[4]
         + fmaxf(pv[5] + __uint_as_float(v.z & 0xFFFF0000u), 0.f) * w[5]
         + fmaxf(pv[6] + __uint_as_float(v.w << 16), 0.f) * w[6]
         + fmaxf(pv[7] + __uint_as_float(v.w & 0xFFFF0000u), 0.f) * w[7];
}

// ---------------- weight prep ----------------
__global__ void prep_weights(const float* __restrict__ gW1, const float* __restrict__ lW1,
                             ushort* __restrict__ W1p, ushort* __restrict__ L1p) {
    int tid = threadIdx.x;
    for (int idx = tid; idx < 64 * 256; idx += 512) {
        int i = idx & 7, c = (idx >> 3) & 255, q = idx >> 11;
        int k = (q >> 2) * 32 + (q & 3) * 8 + i;
        W1p[idx] = f2bf(c < 128 ? gW1[k * 128 + c] : gW1[(64 + k) * 128 + (c - 128)]);
        L1p[idx] = f2bf(c < 128 ? lW1[k * 128 + c] : lW1[(128 + k) * 128 + (c - 128)]);
    }
}

// ---------------- CSR build: fixed-capacity buckets + in-LDS counting sort ----------------
__global__ void bucketA_kernel(const int* __restrict__ eidx, int* __restrict__ bcnt,
                               int2* __restrict__ btmp) {
    int i = blockIdx.x * 256 + threadIdx.x;
    int d = eidx[EE + i], s = eidx[i];
    int bkt = d / NPB;
    int pos = atomicAdd(&bcnt[bkt * 16], 1);
    btmp[(long)bkt * CAP + pos] = make_int2(s, d);
}

__global__ __launch_bounds__(512) void bucket_scan_kernel(const int* __restrict__ bcnt,
                                                          int* __restrict__ bbase) {
    __shared__ int s[NBUCK];
    const int t = threadIdx.x;
    int v = bcnt[t * 16];
    s[t] = v;
    __syncthreads();
    for (int o = 1; o < NBUCK; o <<= 1) {
        int u = (t >= o) ? s[t - o] : 0;
        __syncthreads();
        s[t] += u;
        __syncthreads();
    }
    bbase[t] = s[t] - v;   // exclusive
}

__global__ __launch_bounds__(256) void bucketB_kernel(const int2* __restrict__ btmp,
                                                      const int* __restrict__ bcnt,
                                                      const int* __restrict__ bbase,
                                                      int* __restrict__ offs,
                                                      int* __restrict__ csr) {
    __shared__ int lcnt[NPB];
    __shared__ int lofs[NPB];
    __shared__ int lcur[NPB];
    __shared__ int2 pairs[2048];
    const int bkt = blockIdx.x, tid = threadIdx.x;
    const int cnt = bcnt[bkt * 16];
    const int base = bbase[bkt];
    for (int j = tid; j < NPB; j += 256) lcnt[j] = 0;
    __syncthreads();
    for (int i = tid; i < cnt; i += 256) {
        int2 p = btmp[(long)bkt * CAP + i];
        if (i < 2048) pairs[i] = p;
        atomicAdd(&lcnt[p.y - bkt * NPB], 1);
    }
    __syncthreads();
    if (tid == 0) {
        int run = base;
        for (int j = 0; j < NPB; ++j) { lofs[j] = run; run += lcnt[j]; }
    }
    __syncthreads();
    for (int j = tid; j < NPB; j += 256) {
        lcur[j] = lofs[j];
        offs[bkt * NPB + j] = lofs[j];
    }
    if (bkt == NBUCK - 1 && tid == 0) offs[NN] = EE;
    __syncthreads();
    for (int i = tid; i < cnt; i += 256) {
        int2 p = (i < 2048) ? pairs[i] : btmp[(long)bkt * CAP + i];
        int pos = atomicAdd(&lcur[p.y - bkt * NPB], 1);
        csr[pos] = p.x;
    }
}

// ---------------- node-table GEMM: out[n][0:256] = bf16( x[n]@Wcat + bias_fold + T12[batch[n]] ) ----------------
__global__ __launch_bounds__(512) void pq_gemm(
        const float* __restrict__ x, const ushort* __restrict__ Wp,
        const float* __restrict__ bias1, const float* __restrict__ T12,
        const int* __restrict__ batch, ushort* __restrict__ out) {
    const int tid = threadIdx.x;
    const int w = tid >> 6, l = tid & 63, lr = l & 15, lg = l >> 4;
    const int node = blockIdx.x * 128 + w * 16 + lr;

    short8 xa[2];
#pragma unroll
    for (int ks = 0; ks < 2; ++ks) {
        const float4* bp = reinterpret_cast<const float4*>(x + (long)node * 64 + ks * 32 + lg * 8);
        float4 f0 = bp[0], f1 = bp[1];
        union { short8 s; unsigned int u[4]; } t;
        t.u[0] = cvt_pk_bf16(f0.x, f0.y);
        t.u[1] = cvt_pk_bf16(f0.z, f0.w);
        t.u[2] = cvt_pk_bf16(f1.x, f1.y);
        t.u[3] = cvt_pk_bf16(f1.z, f1.w);
        xa[ks] = t.s;
    }
    f32x4 acc[16];
#pragma unroll
    for (int t = 0; t < 16; ++t)
#pragma unroll
        for (int i = 0; i < 4; ++i)
            acc[t][i] = (t < 8) ? bias1[t * 16 + lg * 4 + i] : 0.f;
#pragma unroll
    for (int ks = 0; ks < 2; ++ks)
#pragma unroll
        for (int t = 0; t < 16; ++t) {
            short8 wf = *reinterpret_cast<const short8*>(Wp + (((ks * 4 + lg) * 256) + t * 16 + lr) * 8);
            acc[t] = __builtin_amdgcn_mfma_f32_16x16x32_bf16(wf, xa[ks], acc[t], 0, 0, 0);
        }
    if (T12) {
        const float* tp = T12 + (long)batch[node] * 256;
#pragma unroll
        for (int t = 0; t < 16; ++t)
#pragma unroll
            for (int i = 0; i < 4; ++i)
                acc[t][i] += tp[t * 16 + lg * 4 + i];
    }
#pragma unroll
    for (int t = 0; t < 16; ++t) {
        uint2 v;
        v.x = cvt_pk_bf16(acc[t][0], acc[t][1]);
        v.y = cvt_pk_bf16(acc[t][2], acc[t][3]);
        *reinterpret_cast<uint2*>(out + (long)node * 256 + t * 16 + lg * 4) = v;
    }
}

// ---------------- global edge pass (CSR, 16 lanes/edge, deep-pipelined dwordx4 gathers) ----------------
__global__ __launch_bounds__(256) void global_edge(
        const ushort* __restrict__ PQ, const int* __restrict__ csr,
        const int* __restrict__ offs, const float* __restrict__ e,
        const int* __restrict__ batch,
        float* __restrict__ hidpart, float* __restrict__ esumpart) {
    const int tid = threadIdx.x;
    const int w = tid >> 6, l = tid & 63, q = l >> 4, c16 = l & 15;
    const int wid = blockIdx.x * 4 + w;
    const int node0 = wid * NPW;
    const int slot = wid & (NS - 1);

    const int offv = offs[node0 + ((l < NPW + 1) ? l : NPW)];
    const float evv = e[node0 + (l & (NPW - 1))];
    const int bv = batch[node0 + (l & (NPW - 1))];

    // upfront: all nodes' first-block src indices + P rows (8 independent loads)
    int srcv0[NPW]; uint4 pdu[NPW];
#pragma unroll
    for (int n = 0; n < NPW; ++n) {
        const int off = __shfl(offv, n, 64);
        const int cnt = __shfl(offv, n + 1, 64) - off;
        const int m = (cnt < 64) ? cnt : 64;
        srcv0[n] = csr[off + ((l < m) ? l : ((m > 0) ? m - 1 : 0))];
        pdu[n] = *reinterpret_cast<const uint4*>(PQ + (long)(node0 + n) * 256 + c16 * 8);
    }

    float accp[8];
#pragma unroll
    for (int j = 0; j < 8; ++j) accp[j] = 0.f;
    float eacc = 0.f;
    int curb = __shfl(bv, 0, 64);

#pragma unroll
    for (int n = 0; n < NPW; ++n) {
        const int off = __shfl(offv, n, 64);
        const int cnt = __shfl(offv, n + 1, 64) - off;
        const int bb  = __shfl(bv, n, 64);
        const float ev = __shfl(evv, n, 64);
        if (bb != curb) {   // flush (wave-uniform)
#pragma unroll
            for (int j = 0; j < 8; ++j) {
                accp[j] += __shfl_xor(accp[j], 16, 64);
                accp[j] += __shfl_xor(accp[j], 32, 64);
            }
            float* hp = hidpart + (long)slot * (BB * 128) + curb * 128 + c16 * 8;
            if (q == 0) {
#pragma unroll
                for (int j = 0; j < 8; ++j) atomicAdd(hp + j, accp[j]);
            }
            if (l == 0) atomicAdd(&esumpart[slot * BB + curb], eacc);
#pragma unroll
            for (int j = 0; j < 8; ++j) accp[j] = 0.f;
            eacc = 0.f;
            curb = bb;
        }
        if (cnt <= 0) continue;
        float pv[8];
        unpack8(pdu[n], pv);
        float h[8];
#pragma unroll
        for (int j = 0; j < 8; ++j) h[j] = 0.f;
        for (int g0 = 0; g0 < cnt; g0 += 64) {
            const int m = (cnt - g0 < 64) ? (cnt - g0) : 64;
            const int sv = (g0 == 0) ? srcv0[n]
                                     : csr[off + g0 + ((l < m) ? l : (m - 1))];
            uint4 qa = ldQ(PQ, __shfl(sv, (q < m) ? q : (m - 1), 64), c16);
            uint4 qb = ldQ(PQ, __shfl(sv, (4 + q < m) ? 4 + q : (m - 1), 64), c16);
            for (int jj = 0; jj < m; jj += 8) {
                uint4 na = qa, nb = qb;
                if (jj + 8 < m) {   // depth-2 prefetch: 2 more loads in flight
                    na = ldQ(PQ, __shfl(sv, (jj + 8 + q < m) ? jj + 8 + q : (m - 1), 64), c16);
                    nb = ldQ(PQ, __shfl(sv, (jj + 12 + q < m) ? jj + 12 + q : (m - 1), 64), c16);
                }
                if (jj + q < m) acc_relu8(pv, qa, h);
                if (jj + 4 + q < m) acc_relu8(pv, qb, h);
                qa = na; qb = nb;
            }
        }
#pragma unroll
        for (int j = 0; j < 8; ++j) accp[j] += ev * h[j];
        eacc += ev * (float)cnt;
    }
    {   // final flush
#pragma unroll
        for (int j = 0; j < 8; ++j) {
            accp[j] += __shfl_xor(accp[j], 16, 64);
            accp[j] += __shfl_xor(accp[j], 32, 64);
        }
        float* hp = hidpart + (long)slot * (BB * 128) + curb * 128 + c16 * 8;
        if (q == 0) {
#pragma unroll
            for (int j = 0; j < 8; ++j) atomicAdd(hp + j, accp[j]);
        }
        if (l == 0) atomicAdd(&esumpart[slot * BB + curb], eacc);
    }
}

// ---------------- fused: hidsum reduce -> pooled (LDS only) -> T12 ----------------
__global__ __launch_bounds__(256) void pooled_t12_kernel(
        const float* __restrict__ hidpart, const float* __restrict__ esumpart,
        const float* __restrict__ gW2, const float* __restrict__ gb2,
        const float* __restrict__ lW1, float* __restrict__ T12) {
    __shared__ float hs[128];
    __shared__ float qacc[4][64];
    __shared__ float pb[64];
    __shared__ float esv;
    const int b = blockIdx.x, tid = threadIdx.x;
    if (tid < 128) {
        float s = 0.f;
        for (int sl = 0; sl < NS; ++sl) s += hidpart[(long)sl * (BB * 128) + b * 128 + tid];
        hs[tid] = s;
    } else if (tid == 128) {
        float s = 0.f;
        for (int sl = 0; sl < NS; ++sl) s += esumpart[sl * BB + b];
        esv = s;
    }
    __syncthreads();
    {
        int col = tid & 63, qr = tid >> 6;
        float a = 0.f;
        for (int k = qr * 32; k < qr * 32 + 32; ++k) a += hs[k] * gW2[k * 64 + col];
        qacc[qr][col] = a;
    }
    __syncthreads();
    if (tid < 64) pb[tid] = qacc[0][tid] + qacc[1][tid] + qacc[2][tid] + qacc[3][tid] + esv * gb2[tid];
    __syncthreads();
    const float* col = (tid < 128) ? (lW1 + 64 * 128 + tid) : (lW1 + 192 * 128 + (tid - 128));
    float acc = 0.f;
    for (int k = 0; k < 64; ++k) acc += pb[k] * col[k * 128];
    T12[b * 256 + tid] = acc;
}

// ---------------- local edge pass (CSR, 16 lanes/edge, deep-pipelined dwordx4 gathers) ----------------
__global__ __launch_bounds__(256) void local_edge(
        const ushort* __restrict__ PQL, const int* __restrict__ csr,
        const int* __restrict__ offs, const float* __restrict__ lW2,
        const float* __restrict__ lb2, float* __restrict__ out) {
    const int tid = threadIdx.x;
    const int w = tid >> 6, l = tid & 63, q = l >> 4, c16 = l & 15;
    const int wid = blockIdx.x * 4 + w;
    const int node0 = wid * NPW;
    const int offv = offs[node0 + ((l < NPW + 1) ? l : NPW)];
    float w2r[8];
#pragma unroll
    for (int j = 0; j < 8; ++j) w2r[j] = lW2[c16 * 8 + j];
    const float b2v = lb2[0];

    int srcv0[NPW]; uint4 pdu[NPW];
#pragma unroll
    for (int n = 0; n < NPW; ++n) {
        const int off = __shfl(offv, n, 64);
        const int cnt = __shfl(offv, n + 1, 64) - off;
        const int m = (cnt < 64) ? cnt : 64;
        srcv0[n] = csr[off + ((l < m) ? l : ((m > 0) ? m - 1 : 0))];
        pdu[n] = *reinterpret_cast<const uint4*>(PQL + (long)(node0 + n) * 256 + c16 * 8);
    }

#pragma unroll
    for (int n = 0; n < NPW; ++n) {
        const int off = __shfl(offv, n, 64);
        const int cnt = __shfl(offv, n + 1, 64) - off;
        float dacc = 0.f;
        if (cnt > 0) {
            float pv[8];
            unpack8(pdu[n], pv);
            for (int g0 = 0; g0 < cnt; g0 += 64) {
                const int m = (cnt - g0 < 64) ? (cnt - g0) : 64;
                const int sv = (g0 == 0) ? srcv0[n]
                                         : csr[off + g0 + ((l < m) ? l : (m - 1))];
                uint4 qa = ldQ(PQL, __shfl(sv, (q < m) ? q : (m - 1), 64), c16);
                uint4 qb = ldQ(PQL, __shfl(sv, (4 + q < m) ? 4 + q : (m - 1), 64), c16);
                for (int jj = 0; jj < m; jj += 8) {
                    uint4 na = qa, nb = qb;
                    if (jj + 8 < m) {
                        na = ldQ(PQL, __shfl(sv, (jj + 8 + q < m) ? jj + 8 + q : (m - 1), 64), c16);
                        nb = ldQ(PQL, __shfl(sv, (jj + 12 + q < m) ? jj + 12 + q : (m - 1), 64), c16);
                    }
                    if (jj + q < m) dacc += dot_relu8(pv, qa, w2r);
                    if (jj + 4 + q < m) dacc += dot_relu8(pv, qb, w2r);
                    qa = na; qb = nb;
                }
            }
            dacc += __shfl_xor(dacc, 1, 64);
            dacc += __shfl_xor(dacc, 2, 64);
            dacc += __shfl_xor(dacc, 4, 64);
            dacc += __shfl_xor(dacc, 8, 64);
            dacc += __shfl_xor(dacc, 16, 64);
            dacc += __shfl_xor(dacc, 32, 64);
        }
        if (l == 0) out[node0 + n] = dacc + (float)cnt * b2v;
    }
}

extern "C" void kernel_launch(void* const* d_in, const int* in_sizes, int n_in,
                              void* d_out, int out_size, void* d_ws, size_t ws_size,
                              hipStream_t stream) {
    const float* x   = (const float*)d_in[0];
    const float* e   = (const float*)d_in[1];
    const int*   ei  = (const int*)d_in[2];
    const int*   bat = (const int*)d_in[3];
    const float* gW1 = (const float*)d_in[4];
    const float* gb1 = (const float*)d_in[5];
    const float* gW2 = (const float*)d_in[6];
    const float* gb2 = (const float*)d_in[7];
    const float* lW1 = (const float*)d_in[8];
    const float* lb1 = (const float*)d_in[9];
    const float* lW2 = (const float*)d_in[10];
    const float* lb2 = (const float*)d_in[11];

    char* ws = (char*)d_ws;
    ushort* W1p     = (ushort*)(ws);                     //    32768 B
    ushort* L1p     = (ushort*)(ws + 32768);             //    32768 B
    float*  T12     = (float*)(ws + 65536);              //    65536 B
    float*  esumpart= (float*)(ws + 131072);             //     8192 B
    float*  hidpart = (float*)(ws + 139264);             //  1048576 B
    int*    offs    = (int*)(ws + 1187840);              //   204832 B (51201 ints)
    int*    bcnt    = (int*)(ws + 1392672);              //    32768 B (512 line-padded)
    int*    bbase   = (int*)(ws + 1425440);              //     2048 B
    int*    csr     = (int*)(ws + 1427488);              //  3276800 B
    ushort* PQ      = (ushort*)(ws + 4704288);           // 26214400 B (btmp overlays; reused for PQL)
    int2*   btmp    = (int2*)PQ;                         // 512*4096*8 = 16777216 B, consumed before pq_gemm

    hipMemsetAsync(bcnt, 0, 32768, stream);
    hipMemsetAsync(esumpart, 0, 8192 + 1048576, stream);           // esumpart + hidpart
    hipMemsetAsync(d_out, 0, (size_t)out_size * sizeof(float), stream);

    prep_weights<<<1, 512, 0, stream>>>(gW1, lW1, W1p, L1p);
    bucketA_kernel<<<EE / 256, 256, 0, stream>>>(ei, bcnt, btmp);
    bucket_scan_kernel<<<1, NBUCK, 0, stream>>>(bcnt, bbase);
    bucketB_kernel<<<NBUCK, 256, 0, stream>>>(btmp, bcnt, bbase, offs, csr);

    pq_gemm<<<NN / 128, 512, 0, stream>>>(x, W1p, gb1, nullptr, bat, PQ);
    global_edge<<<NN / (4 * NPW), 256, 0, stream>>>(PQ, csr, offs, e, bat, hidpart, esumpart);
    pooled_t12_kernel<<<BB, 256, 0, stream>>>(hidpart, esumpart, gW2, gb2, lW1, T12);
    pq_gemm<<<NN / 128, 512, 0, stream>>>(x, L1p, lb1, T12, bat, PQ);   // -> PQL
    local_edge<<<NN / (4 * NPW), 256, 0, stream>>>(PQ, csr, offs, lW2, lb2, (float*)d_out);
}

// Round 9
// 204.447 us; speedup vs baseline: 1.7698x; 1.2653x over previous
//
#include <hip/hip_runtime.h>
#include <hip/hip_bf16.h>

#define NN 51200
#define EE 819200
#define BB 64
#define NS 32
#define NPW 8       // nodes per wave in edge passes
#define NBUCK 512   // dst-range buckets for scatter
#define NPB 100     // nodes per bucket = NN/NBUCK
#define CAP 4096    // bucket capacity (mean 1600, std ~40)

typedef __attribute__((ext_vector_type(8))) short short8;
typedef __attribute__((ext_vector_type(4))) float f32x4;

__device__ __forceinline__ ushort f2bf(float f) {
    unsigned int u = __float_as_uint(f);
    unsigned int r = (u + 0x7FFFu + ((u >> 16) & 1u)) >> 16;   // RNE, finite inputs
    return (ushort)r;
}
__device__ __forceinline__ unsigned int cvt_pk_bf16(float lo, float hi) {
    unsigned int r;
    asm("v_cvt_pk_bf16_f32 %0, %1, %2" : "=v"(r) : "v"(lo), "v"(hi));
    return r;
}

// ---------------- weight prep ----------------
__global__ void prep_weights(const float* __restrict__ gW1, const float* __restrict__ lW1,
                             ushort* __restrict__ W1p, ushort* __restrict__ L1p) {
    int tid = threadIdx.x;
    for (int idx = tid; idx < 64 * 256; idx += 512) {
        int i = idx & 7, c = (idx >> 3) & 255, q = idx >> 11;
        int k = (q >> 2) * 32 + (q & 3) * 8 + i;
        W1p[idx] = f2bf(c < 128 ? gW1[k * 128 + c] : gW1[(64 + k) * 128 + (c - 128)]);
        L1p[idx] = f2bf(c < 128 ? lW1[k * 128 + c] : lW1[(128 + k) * 128 + (c - 128)]);
    }
}

// ---------------- CSR build: fixed-capacity buckets + in-LDS counting sort ----------------
__global__ void bucketA_kernel(const int* __restrict__ eidx, int* __restrict__ bcnt,
                               int2* __restrict__ btmp) {
    int i = blockIdx.x * 256 + threadIdx.x;
    int d = eidx[EE + i], s = eidx[i];
    int bkt = d / NPB;
    int pos = atomicAdd(&bcnt[bkt * 16], 1);
    btmp[(long)bkt * CAP + pos] = make_int2(s, d);
}

__global__ __launch_bounds__(512) void bucket_scan_kernel(const int* __restrict__ bcnt,
                                                          int* __restrict__ bbase) {
    __shared__ int s[NBUCK];
    const int t = threadIdx.x;
    int v = bcnt[t * 16];
    s[t] = v;
    __syncthreads();
    for (int o = 1; o < NBUCK; o <<= 1) {
        int u = (t >= o) ? s[t - o] : 0;
        __syncthreads();
        s[t] += u;
        __syncthreads();
    }
    bbase[t] = s[t] - v;   // exclusive
}

__global__ __launch_bounds__(256) void bucketB_kernel(const int2* __restrict__ btmp,
                                                      const int* __restrict__ bcnt,
                                                      const int* __restrict__ bbase,
                                                      int* __restrict__ offs,
                                                      int* __restrict__ csr) {
    __shared__ int lcnt[NPB];
    __shared__ int lofs[NPB];
    __shared__ int lcur[NPB];
    __shared__ int2 pairs[2048];
    const int bkt = blockIdx.x, tid = threadIdx.x;
    const int cnt = bcnt[bkt * 16];
    const int base = bbase[bkt];
    for (int j = tid; j < NPB; j += 256) lcnt[j] = 0;
    __syncthreads();
    for (int i = tid; i < cnt; i += 256) {
        int2 p = btmp[(long)bkt * CAP + i];
        if (i < 2048) pairs[i] = p;
        atomicAdd(&lcnt[p.y - bkt * NPB], 1);
    }
    __syncthreads();
    if (tid == 0) {
        int run = base;
        for (int j = 0; j < NPB; ++j) { lofs[j] = run; run += lcnt[j]; }
    }
    __syncthreads();
    for (int j = tid; j < NPB; j += 256) {
        lcur[j] = lofs[j];
        offs[bkt * NPB + j] = lofs[j];
    }
    if (bkt == NBUCK - 1 && tid == 0) offs[NN] = EE;
    __syncthreads();
    for (int i = tid; i < cnt; i += 256) {
        int2 p = (i < 2048) ? pairs[i] : btmp[(long)bkt * CAP + i];
        int pos = atomicAdd(&lcur[p.y - bkt * NPB], 1);
        csr[pos] = p.x;
    }
}

// ---------------- node-table GEMM: out[n][0:256] = bf16( x[n]@Wcat + bias_fold + T12[batch[n]] ) ----------------
__global__ __launch_bounds__(512) void pq_gemm(
        const float* __restrict__ x, const ushort* __restrict__ Wp,
        const float* __restrict__ bias1, const float* __restrict__ T12,
        const int* __restrict__ batch, ushort* __restrict__ out) {
    const int tid = threadIdx.x;
    const int w = tid >> 6, l = tid & 63, lr = l & 15, lg = l >> 4;
    const int node = blockIdx.x * 128 + w * 16 + lr;

    short8 xa[2];
#pragma unroll
    for (int ks = 0; ks < 2; ++ks) {
        const float4* bp = reinterpret_cast<const float4*>(x + (long)node * 64 + ks * 32 + lg * 8);
        float4 f0 = bp[0], f1 = bp[1];
        union { short8 s; unsigned int u[4]; } t;
        t.u[0] = cvt_pk_bf16(f0.x, f0.y);
        t.u[1] = cvt_pk_bf16(f0.z, f0.w);
        t.u[2] = cvt_pk_bf16(f1.x, f1.y);
        t.u[3] = cvt_pk_bf16(f1.z, f1.w);
        xa[ks] = t.s;
    }
    f32x4 acc[16];
#pragma unroll
    for (int t = 0; t < 16; ++t)
#pragma unroll
        for (int i = 0; i < 4; ++i)
            acc[t][i] = (t < 8) ? bias1[t * 16 + lg * 4 + i] : 0.f;
#pragma unroll
    for (int ks = 0; ks < 2; ++ks)
#pragma unroll
        for (int t = 0; t < 16; ++t) {
            short8 wf = *reinterpret_cast<const short8*>(Wp + (((ks * 4 + lg) * 256) + t * 16 + lr) * 8);
            acc[t] = __builtin_amdgcn_mfma_f32_16x16x32_bf16(wf, xa[ks], acc[t], 0, 0, 0);
        }
    if (T12) {
        const float* tp = T12 + (long)batch[node] * 256;
#pragma unroll
        for (int t = 0; t < 16; ++t)
#pragma unroll
            for (int i = 0; i < 4; ++i)
                acc[t][i] += tp[t * 16 + lg * 4 + i];
    }
#pragma unroll
    for (int t = 0; t < 16; ++t) {
        uint2 v;
        v.x = cvt_pk_bf16(acc[t][0], acc[t][1]);
        v.y = cvt_pk_bf16(acc[t][2], acc[t][3]);
        *reinterpret_cast<uint2*>(out + (long)node * 256 + t * 16 + lg * 4) = v;
    }
}

// ---------------- global edge pass (CSR): 2 ch/lane, depth-8 gather batch, reg pooling ----------------
__global__ __launch_bounds__(256) void global_edge(
        const ushort* __restrict__ PQ, const int* __restrict__ csr,
        const int* __restrict__ offs, const float* __restrict__ e,
        const int* __restrict__ batch,
        float* __restrict__ hidpart, float* __restrict__ esumpart) {
    const int tid = threadIdx.x;
    const int w = tid >> 6, l = tid & 63;
    const int wid = blockIdx.x * 4 + w;
    const int node0 = wid * NPW;
    const int slot = wid & (NS - 1);

    const int offv = offs[node0 + ((l < NPW + 1) ? l : NPW)];
    const float evv = e[node0 + (l & (NPW - 1))];
    const int bv = batch[node0 + (l & (NPW - 1))];

    float accp0 = 0.f, accp1 = 0.f, eacc = 0.f;
    int curb = __shfl(bv, 0, 64);

    for (int n = 0; n < NPW; ++n) {
        const int off = __shfl(offv, n, 64);
        const int cnt = __shfl(offv, n + 1, 64) - off;
        const int bb  = __shfl(bv, n, 64);
        const float ev = __shfl(evv, n, 64);
        if (bb != curb) {   // flush (wave-uniform)
            float* hp = hidpart + (long)slot * (BB * 128) + curb * 128;
            atomicAdd(hp + 2 * l, accp0);
            atomicAdd(hp + 2 * l + 1, accp1);
            if (l == 0) atomicAdd(&esumpart[slot * BB + curb], eacc);
            accp0 = accp1 = eacc = 0.f;
            curb = bb;
        }
        if (cnt <= 0) continue;
        const unsigned int pdu = *reinterpret_cast<const unsigned int*>(PQ + (long)(node0 + n) * 256 + 2 * l);
        const float p0 = __uint_as_float(pdu << 16);
        const float p1 = __uint_as_float(pdu & 0xFFFF0000u);
        float h0 = 0.f, h1 = 0.f;
        for (int g0 = 0; g0 < cnt; g0 += 64) {
            const int m = (cnt - g0 < 64) ? (cnt - g0) : 64;
            const int srcv = csr[off + g0 + ((l < m) ? l : (m - 1))];
            for (int jj = 0; jj < m; jj += 8) {
                unsigned int qv[8];
#pragma unroll
                for (int k = 0; k < 8; ++k) {      // 8 independent gathers in flight
                    int kk = jj + k; if (kk > m - 1) kk = m - 1;
                    const int s = __shfl(srcv, kk, 64);
                    qv[k] = *reinterpret_cast<const unsigned int*>(PQ + (long)s * 256 + 128 + 2 * l);
                }
#pragma unroll
                for (int k = 0; k < 8; ++k) {
                    const float q0 = __uint_as_float(qv[k] << 16);
                    const float q1 = __uint_as_float(qv[k] & 0xFFFF0000u);
                    const float r0 = fmaxf(p0 + q0, 0.f);
                    const float r1 = fmaxf(p1 + q1, 0.f);
                    if (jj + k < m) { h0 += r0; h1 += r1; }
                }
            }
        }
        accp0 += ev * h0; accp1 += ev * h1; eacc += ev * (float)cnt;
    }
    {   // final flush
        float* hp = hidpart + (long)slot * (BB * 128) + curb * 128;
        atomicAdd(hp + 2 * l, accp0);
        atomicAdd(hp + 2 * l + 1, accp1);
        if (l == 0) atomicAdd(&esumpart[slot * BB + curb], eacc);
    }
}

// ---------------- fused: hidsum reduce -> pooled (LDS only) -> T12 ----------------
__global__ __launch_bounds__(256) void pooled_t12_kernel(
        const float* __restrict__ hidpart, const float* __restrict__ esumpart,
        const float* __restrict__ gW2, const float* __restrict__ gb2,
        const float* __restrict__ lW1, float* __restrict__ T12) {
    __shared__ float hs[128];
    __shared__ float qacc[4][64];
    __shared__ float pb[64];
    __shared__ float esv;
    const int b = blockIdx.x, tid = threadIdx.x;
    if (tid < 128) {
        float s = 0.f;
        for (int sl = 0; sl < NS; ++sl) s += hidpart[(long)sl * (BB * 128) + b * 128 + tid];
        hs[tid] = s;
    } else if (tid == 128) {
        float s = 0.f;
        for (int sl = 0; sl < NS; ++sl) s += esumpart[sl * BB + b];
        esv = s;
    }
    __syncthreads();
    {
        int col = tid & 63, qr = tid >> 6;
        float a = 0.f;
        for (int k = qr * 32; k < qr * 32 + 32; ++k) a += hs[k] * gW2[k * 64 + col];
        qacc[qr][col] = a;
    }
    __syncthreads();
    if (tid < 64) pb[tid] = qacc[0][tid] + qacc[1][tid] + qacc[2][tid] + qacc[3][tid] + esv * gb2[tid];
    __syncthreads();
    const float* col = (tid < 128) ? (lW1 + 64 * 128 + tid) : (lW1 + 192 * 128 + (tid - 128));
    float acc = 0.f;
    for (int k = 0; k < 64; ++k) acc += pb[k] * col[k * 128];
    T12[b * 256 + tid] = acc;
}

// ---------------- local edge pass (CSR): 2 ch/lane, depth-8 gather batch ----------------
__global__ __launch_bounds__(256) void local_edge(
        const ushort* __restrict__ PQL, const int* __restrict__ csr,
        const int* __restrict__ offs, const float* __restrict__ lW2,
        const float* __restrict__ lb2, float* __restrict__ out) {
    const int tid = threadIdx.x;
    const int w = tid >> 6, l = tid & 63;
    const int wid = blockIdx.x * 4 + w;
    const int node0 = wid * NPW;
    const int offv = offs[node0 + ((l < NPW + 1) ? l : NPW)];
    const float w20 = lW2[2 * l], w21 = lW2[2 * l + 1];
    const float b2v = lb2[0];

    for (int n = 0; n < NPW; ++n) {
        const int off = __shfl(offv, n, 64);
        const int cnt = __shfl(offv, n + 1, 64) - off;
        float dacc = 0.f;
        if (cnt > 0) {
            const unsigned int pdu = *reinterpret_cast<const unsigned int*>(PQL + (long)(node0 + n) * 256 + 2 * l);
            const float p0 = __uint_as_float(pdu << 16);
            const float p1 = __uint_as_float(pdu & 0xFFFF0000u);
            for (int g0 = 0; g0 < cnt; g0 += 64) {
                const int m = (cnt - g0 < 64) ? (cnt - g0) : 64;
                const int srcv = csr[off + g0 + ((l < m) ? l : (m - 1))];
                for (int jj = 0; jj < m; jj += 8) {
                    unsigned int qv[8];
#pragma unroll
                    for (int k = 0; k < 8; ++k) {
                        int kk = jj + k; if (kk > m - 1) kk = m - 1;
                        const int s = __shfl(srcv, kk, 64);
                        qv[k] = *reinterpret_cast<const unsigned int*>(PQL + (long)s * 256 + 128 + 2 * l);
                    }
#pragma unroll
                    for (int k = 0; k < 8; ++k) {
                        const float q0 = __uint_as_float(qv[k] << 16);
                        const float q1 = __uint_as_float(qv[k] & 0xFFFF0000u);
                        const float t0 = fmaxf(p0 + q0, 0.f) * w20 + fmaxf(p1 + q1, 0.f) * w21;
                        if (jj + k < m) dacc += t0;
                    }
                }
            }
            dacc += __shfl_xor(dacc, 1, 64);
            dacc += __shfl_xor(dacc, 2, 64);
            dacc += __shfl_xor(dacc, 4, 64);
            dacc += __shfl_xor(dacc, 8, 64);
            dacc += __shfl_xor(dacc, 16, 64);
            dacc += __shfl_xor(dacc, 32, 64);
        }
        if (l == 0) out[node0 + n] = dacc + (float)cnt * b2v;
    }
}

extern "C" void kernel_launch(void* const* d_in, const int* in_sizes, int n_in,
                              void* d_out, int out_size, void* d_ws, size_t ws_size,
                              hipStream_t stream) {
    const float* x   = (const float*)d_in[0];
    const float* e   = (const float*)d_in[1];
    const int*   ei  = (const int*)d_in[2];
    const int*   bat = (const int*)d_in[3];
    const float* gW1 = (const float*)d_in[4];
    const float* gb1 = (const float*)d_in[5];
    const float* gW2 = (const float*)d_in[6];
    const float* gb2 = (const float*)d_in[7];
    const float* lW1 = (const float*)d_in[8];
    const float* lb1 = (const float*)d_in[9];
    const float* lW2 = (const float*)d_in[10];
    const float* lb2 = (const float*)d_in[11];

    char* ws = (char*)d_ws;
    ushort* W1p     = (ushort*)(ws);                     //    32768 B
    ushort* L1p     = (ushort*)(ws + 32768);             //    32768 B
    float*  T12     = (float*)(ws + 65536);              //    65536 B
    float*  esumpart= (float*)(ws + 131072);             //     8192 B
    float*  hidpart = (float*)(ws + 139264);             //  1048576 B
    int*    offs    = (int*)(ws + 1187840);              //   204832 B (51201 ints)
    int*    bcnt    = (int*)(ws + 1392672);              //    32768 B (512 line-padded)
    int*    bbase   = (int*)(ws + 1425440);              //     2048 B
    int*    csr     = (int*)(ws + 1427488);              //  3276800 B
    ushort* PQ      = (ushort*)(ws + 4704288);           // 26214400 B (btmp overlays; reused for PQL)
    int2*   btmp    = (int2*)PQ;                         // 512*4096*8 = 16777216 B, consumed before pq_gemm

    hipMemsetAsync(bcnt, 0, 32768, stream);
    hipMemsetAsync(esumpart, 0, 8192 + 1048576, stream);           // esumpart + hidpart
    hipMemsetAsync(d_out, 0, (size_t)out_size * sizeof(float), stream);

    prep_weights<<<1, 512, 0, stream>>>(gW1, lW1, W1p, L1p);
    bucketA_kernel<<<EE / 256, 256, 0, stream>>>(ei, bcnt, btmp);
    bucket_scan_kernel<<<1, NBUCK, 0, stream>>>(bcnt, bbase);
    bucketB_kernel<<<NBUCK, 256, 0, stream>>>(btmp, bcnt, bbase, offs, csr);

    pq_gemm<<<NN / 128, 512, 0, stream>>>(x, W1p, gb1, nullptr, bat, PQ);
    global_edge<<<NN / (4 * NPW), 256, 0, stream>>>(PQ, csr, offs, e, bat, hidpart, esumpart);
    pooled_t12_kernel<<<BB, 256, 0, stream>>>(hidpart, esumpart, gW2, gb2, lW1, T12);
    pq_gemm<<<NN / 128, 512, 0, stream>>>(x, L1p, lb1, T12, bat, PQ);   // -> PQL
    local_edge<<<NN / (4 * NPW), 256, 0, stream>>>(PQ, csr, offs, lW2, lb2, (float*)d_out);
}

// Round 10
// 201.536 us; speedup vs baseline: 1.7954x; 1.0144x over previous
//
#include <hip/hip_runtime.h>
#include <hip/hip_bf16.h>

#define NN 51200
#define EE 819200
#define BB 64
#define NS 32
#define NPWG 8      // nodes per wave, global edge pass
#define NPWL 4      // nodes per wave, local edge pass
#define NBUCK 512   // dst-range buckets for scatter
#define NPB 100     // nodes per bucket = NN/NBUCK
#define CAP 4096    // bucket capacity (mean 1600, std ~40)

typedef __attribute__((ext_vector_type(8))) short short8;
typedef __attribute__((ext_vector_type(4))) float f32x4;

__device__ __forceinline__ ushort f2bf(float f) {
    unsigned int u = __float_as_uint(f);
    unsigned int r = (u + 0x7FFFu + ((u >> 16) & 1u)) >> 16;   // RNE, finite inputs
    return (ushort)r;
}
__device__ __forceinline__ unsigned int cvt_pk_bf16(float lo, float hi) {
    unsigned int r;
    asm("v_cvt_pk_bf16_f32 %0, %1, %2" : "=v"(r) : "v"(lo), "v"(hi));
    return r;
}

// ---------------- weight prep ----------------
__global__ void prep_weights(const float* __restrict__ gW1, const float* __restrict__ lW1,
                             ushort* __restrict__ W1p, ushort* __restrict__ L1p) {
    int tid = threadIdx.x;
    for (int idx = tid; idx < 64 * 256; idx += 512) {
        int i = idx & 7, c = (idx >> 3) & 255, q = idx >> 11;
        int k = (q >> 2) * 32 + (q & 3) * 8 + i;
        W1p[idx] = f2bf(c < 128 ? gW1[k * 128 + c] : gW1[(64 + k) * 128 + (c - 128)]);
        L1p[idx] = f2bf(c < 128 ? lW1[k * 128 + c] : lW1[(128 + k) * 128 + (c - 128)]);
    }
}

// ---------------- CSR build: fixed-capacity buckets + in-LDS counting sort ----------------
__global__ void bucketA_kernel(const int* __restrict__ eidx, int* __restrict__ bcnt,
                               int2* __restrict__ btmp) {
    int i = blockIdx.x * 256 + threadIdx.x;
    int d = eidx[EE + i], s = eidx[i];
    int bkt = d / NPB;
    int pos = atomicAdd(&bcnt[bkt * 16], 1);
    btmp[(long)bkt * CAP + pos] = make_int2(s, d);
}

__global__ __launch_bounds__(512) void bucket_scan_kernel(const int* __restrict__ bcnt,
                                                          int* __restrict__ bbase) {
    __shared__ int s[NBUCK];
    const int t = threadIdx.x;
    int v = bcnt[t * 16];
    s[t] = v;
    __syncthreads();
    for (int o = 1; o < NBUCK; o <<= 1) {
        int u = (t >= o) ? s[t - o] : 0;
        __syncthreads();
        s[t] += u;
        __syncthreads();
    }
    bbase[t] = s[t] - v;   // exclusive
}

__global__ __launch_bounds__(256) void bucketB_kernel(const int2* __restrict__ btmp,
                                                      const int* __restrict__ bcnt,
                                                      const int* __restrict__ bbase,
                                                      int* __restrict__ offs,
                                                      int* __restrict__ csr) {
    __shared__ int lcnt[NPB];
    __shared__ int lofs[NPB];
    __shared__ int lcur[NPB];
    __shared__ int2 pairs[2048];
    const int bkt = blockIdx.x, tid = threadIdx.x;
    const int cnt = bcnt[bkt * 16];
    const int base = bbase[bkt];
    for (int j = tid; j < NPB; j += 256) lcnt[j] = 0;
    __syncthreads();
    for (int i = tid; i < cnt; i += 256) {
        int2 p = btmp[(long)bkt * CAP + i];
        if (i < 2048) pairs[i] = p;
        atomicAdd(&lcnt[p.y - bkt * NPB], 1);
    }
    __syncthreads();
    if (tid == 0) {
        int run = base;
        for (int j = 0; j < NPB; ++j) { lofs[j] = run; run += lcnt[j]; }
    }
    __syncthreads();
    for (int j = tid; j < NPB; j += 256) {
        lcur[j] = lofs[j];
        offs[bkt * NPB + j] = lofs[j];
    }
    if (bkt == NBUCK - 1 && tid == 0) offs[NN] = EE;
    __syncthreads();
    for (int i = tid; i < cnt; i += 256) {
        int2 p = (i < 2048) ? pairs[i] : btmp[(long)bkt * CAP + i];
        int pos = atomicAdd(&lcur[p.y - bkt * NPB], 1);
        csr[pos] = p.x;
    }
}

// ---------------- node-table GEMM: out[n][0:256] = bf16( x[n]@Wcat + bias_fold + T12[batch[n]] ) ----------------
__global__ __launch_bounds__(512) void pq_gemm(
        const float* __restrict__ x, const ushort* __restrict__ Wp,
        const float* __restrict__ bias1, const float* __restrict__ T12,
        const int* __restrict__ batch, ushort* __restrict__ out) {
    const int tid = threadIdx.x;
    const int w = tid >> 6, l = tid & 63, lr = l & 15, lg = l >> 4;
    const int node = blockIdx.x * 128 + w * 16 + lr;

    short8 xa[2];
#pragma unroll
    for (int ks = 0; ks < 2; ++ks) {
        const float4* bp = reinterpret_cast<const float4*>(x + (long)node * 64 + ks * 32 + lg * 8);
        float4 f0 = bp[0], f1 = bp[1];
        union { short8 s; unsigned int u[4]; } t;
        t.u[0] = cvt_pk_bf16(f0.x, f0.y);
        t.u[1] = cvt_pk_bf16(f0.z, f0.w);
        t.u[2] = cvt_pk_bf16(f1.x, f1.y);
        t.u[3] = cvt_pk_bf16(f1.z, f1.w);
        xa[ks] = t.s;
    }
    f32x4 acc[16];
#pragma unroll
    for (int t = 0; t < 16; ++t)
#pragma unroll
        for (int i = 0; i < 4; ++i)
            acc[t][i] = (t < 8) ? bias1[t * 16 + lg * 4 + i] : 0.f;
#pragma unroll
    for (int ks = 0; ks < 2; ++ks)
#pragma unroll
        for (int t = 0; t < 16; ++t) {
            short8 wf = *reinterpret_cast<const short8*>(Wp + (((ks * 4 + lg) * 256) + t * 16 + lr) * 8);
            acc[t] = __builtin_amdgcn_mfma_f32_16x16x32_bf16(wf, xa[ks], acc[t], 0, 0, 0);
        }
    if (T12) {
        const float* tp = T12 + (long)batch[node] * 256;
#pragma unroll
        for (int t = 0; t < 16; ++t)
#pragma unroll
            for (int i = 0; i < 4; ++i)
                acc[t][i] += tp[t * 16 + lg * 4 + i];
    }
#pragma unroll
    for (int t = 0; t < 16; ++t) {
        uint2 v;
        v.x = cvt_pk_bf16(acc[t][0], acc[t][1]);
        v.y = cvt_pk_bf16(acc[t][2], acc[t][3]);
        *reinterpret_cast<uint2*>(out + (long)node * 256 + t * 16 + lg * 4) = v;
    }
}

// ---------------- global edge pass (CSR): scalarized control, 2 ch/lane, reg pooling ----------------
__global__ __launch_bounds__(256) void global_edge(
        const ushort* __restrict__ PQ, const int* __restrict__ csr,
        const int* __restrict__ offs, const float* __restrict__ e,
        const int* __restrict__ batch,
        float* __restrict__ hidpart, float* __restrict__ esumpart) {
    const int tid = threadIdx.x;
    const int w = tid >> 6, l = tid & 63;
    const int wid = blockIdx.x * 4 + w;
    const int node0 = __builtin_amdgcn_readfirstlane(wid * NPWG);   // SGPR-pin: all control flow scalar
    const int slot = wid & (NS - 1);

    float accp0 = 0.f, accp1 = 0.f, eacc = 0.f;
    int curb = batch[node0];

    for (int n = 0; n < NPWG; ++n) {
        const int node = node0 + n;
        const int off  = offs[node];            // s_load (uniform addr)
        const int cnt  = offs[node + 1] - off;
        const int bb   = batch[node];
        const float ev = e[node];
        if (bb != curb) {                       // uniform branch
            float* hp = hidpart + (long)slot * (BB * 128) + curb * 128;
            atomicAdd(hp + 2 * l, accp0);
            atomicAdd(hp + 2 * l + 1, accp1);
            if (l == 0) atomicAdd(&esumpart[slot * BB + curb], eacc);
            accp0 = accp1 = eacc = 0.f;
            curb = bb;
        }
        if (cnt <= 0) continue;
        const unsigned int pdu = *reinterpret_cast<const unsigned int*>(PQ + (long)node * 256 + 2 * l);
        const float p0 = __uint_as_float(pdu << 16);
        const float p1 = __uint_as_float(pdu & 0xFFFF0000u);
        float h0 = 0.f, h1 = 0.f;
        int g = 0;
        for (; g + 8 <= cnt; g += 8) {          // exact batches: no per-lane predication
            unsigned int qv[8];
#pragma unroll
            for (int k = 0; k < 8; ++k) {
                const int s = csr[off + g + k]; // s_load; folds into gather's SGPR base
                qv[k] = *reinterpret_cast<const unsigned int*>(PQ + (long)s * 256 + 128 + 2 * l);
            }
#pragma unroll
            for (int k = 0; k < 8; ++k) {
                h0 += fmaxf(p0 + __uint_as_float(qv[k] << 16), 0.f);
                h1 += fmaxf(p1 + __uint_as_float(qv[k] & 0xFFFF0000u), 0.f);
            }
        }
        for (; g < cnt; ++g) {                  // scalar tail (<8 edges)
            const int s = csr[off + g];
            const unsigned int qv = *reinterpret_cast<const unsigned int*>(PQ + (long)s * 256 + 128 + 2 * l);
            h0 += fmaxf(p0 + __uint_as_float(qv << 16), 0.f);
            h1 += fmaxf(p1 + __uint_as_float(qv & 0xFFFF0000u), 0.f);
        }
        accp0 += ev * h0; accp1 += ev * h1; eacc += ev * (float)cnt;
    }
    {   // final flush
        float* hp = hidpart + (long)slot * (BB * 128) + curb * 128;
        atomicAdd(hp + 2 * l, accp0);
        atomicAdd(hp + 2 * l + 1, accp1);
        if (l == 0) atomicAdd(&esumpart[slot * BB + curb], eacc);
    }
}

// ---------------- fused: hidsum reduce -> pooled (LDS only) -> T12 ----------------
__global__ __launch_bounds__(256) void pooled_t12_kernel(
        const float* __restrict__ hidpart, const float* __restrict__ esumpart,
        const float* __restrict__ gW2, const float* __restrict__ gb2,
        const float* __restrict__ lW1, float* __restrict__ T12) {
    __shared__ float hs[128];
    __shared__ float qacc[4][64];
    __shared__ float pb[64];
    __shared__ float esv;
    const int b = blockIdx.x, tid = threadIdx.x;
    if (tid < 128) {
        float s = 0.f;
        for (int sl = 0; sl < NS; ++sl) s += hidpart[(long)sl * (BB * 128) + b * 128 + tid];
        hs[tid] = s;
    } else if (tid == 128) {
        float s = 0.f;
        for (int sl = 0; sl < NS; ++sl) s += esumpart[sl * BB + b];
        esv = s;
    }
    __syncthreads();
    {
        int col = tid & 63, qr = tid >> 6;
        float a = 0.f;
        for (int k = qr * 32; k < qr * 32 + 32; ++k) a += hs[k] * gW2[k * 64 + col];
        qacc[qr][col] = a;
    }
    __syncthreads();
    if (tid < 64) pb[tid] = qacc[0][tid] + qacc[1][tid] + qacc[2][tid] + qacc[3][tid] + esv * gb2[tid];
    __syncthreads();
    const float* col = (tid < 128) ? (lW1 + 64 * 128 + tid) : (lW1 + 192 * 128 + (tid - 128));
    float acc = 0.f;
    for (int k = 0; k < 64; ++k) acc += pb[k] * col[k * 128];
    T12[b * 256 + tid] = acc;
}

// ---------------- local edge pass (CSR): scalarized control, 2 ch/lane ----------------
__global__ __launch_bounds__(256) void local_edge(
        const ushort* __restrict__ PQL, const int* __restrict__ csr,
        const int* __restrict__ offs, const float* __restrict__ lW2,
        const float* __restrict__ lb2, float* __restrict__ out) {
    const int tid = threadIdx.x;
    const int w = tid >> 6, l = tid & 63;
    const int wid = blockIdx.x * 4 + w;
    const int node0 = __builtin_amdgcn_readfirstlane(wid * NPWL);
    const float w20 = lW2[2 * l], w21 = lW2[2 * l + 1];
    const float b2v = lb2[0];

    for (int n = 0; n < NPWL; ++n) {
        const int node = node0 + n;
        const int off = offs[node];
        const int cnt = offs[node + 1] - off;
        float dacc = 0.f;
        if (cnt > 0) {
            const unsigned int pdu = *reinterpret_cast<const unsigned int*>(PQL + (long)node * 256 + 2 * l);
            const float p0 = __uint_as_float(pdu << 16);
            const float p1 = __uint_as_float(pdu & 0xFFFF0000u);
            int g = 0;
            for (; g + 8 <= cnt; g += 8) {
                unsigned int qv[8];
#pragma unroll
                for (int k = 0; k < 8; ++k) {
                    const int s = csr[off + g + k];
                    qv[k] = *reinterpret_cast<const unsigned int*>(PQL + (long)s * 256 + 128 + 2 * l);
                }
#pragma unroll
                for (int k = 0; k < 8; ++k) {
                    dacc += fmaxf(p0 + __uint_as_float(qv[k] << 16), 0.f) * w20
                          + fmaxf(p1 + __uint_as_float(qv[k] & 0xFFFF0000u), 0.f) * w21;
                }
            }
            for (; g < cnt; ++g) {
                const int s = csr[off + g];
                const unsigned int qv = *reinterpret_cast<const unsigned int*>(PQL + (long)s * 256 + 128 + 2 * l);
                dacc += fmaxf(p0 + __uint_as_float(qv << 16), 0.f) * w20
                      + fmaxf(p1 + __uint_as_float(qv & 0xFFFF0000u), 0.f) * w21;
            }
            dacc += __shfl_xor(dacc, 1, 64);
            dacc += __shfl_xor(dacc, 2, 64);
            dacc += __shfl_xor(dacc, 4, 64);
            dacc += __shfl_xor(dacc, 8, 64);
            dacc += __shfl_xor(dacc, 16, 64);
            dacc += __shfl_xor(dacc, 32, 64);
        }
        if (l == 0) out[node] = dacc + (float)cnt * b2v;
    }
}

extern "C" void kernel_launch(void* const* d_in, const int* in_sizes, int n_in,
                              void* d_out, int out_size, void* d_ws, size_t ws_size,
                              hipStream_t stream) {
    const float* x   = (const float*)d_in[0];
    const float* e   = (const float*)d_in[1];
    const int*   ei  = (const int*)d_in[2];
    const int*   bat = (const int*)d_in[3];
    const float* gW1 = (const float*)d_in[4];
    const float* gb1 = (const float*)d_in[5];
    const float* gW2 = (const float*)d_in[6];
    const float* gb2 = (const float*)d_in[7];
    const float* lW1 = (const float*)d_in[8];
    const float* lb1 = (const float*)d_in[9];
    const float* lW2 = (const float*)d_in[10];
    const float* lb2 = (const float*)d_in[11];

    char* ws = (char*)d_ws;
    ushort* W1p     = (ushort*)(ws);                     //    32768 B
    ushort* L1p     = (ushort*)(ws + 32768);             //    32768 B
    float*  T12     = (float*)(ws + 65536);              //    65536 B
    float*  esumpart= (float*)(ws + 131072);             //     8192 B
    float*  hidpart = (float*)(ws + 139264);             //  1048576 B
    int*    offs    = (int*)(ws + 1187840);              //   204832 B (51201 ints)
    int*    bcnt    = (int*)(ws + 1392672);              //    32768 B (512 line-padded)
    int*    bbase   = (int*)(ws + 1425440);              //     2048 B
    int*    csr     = (int*)(ws + 1427488);              //  3276800 B
    ushort* PQ      = (ushort*)(ws + 4704288);           // 26214400 B (btmp overlays; reused for PQL)
    int2*   btmp    = (int2*)PQ;                         // 512*4096*8 = 16777216 B, consumed before pq_gemm

    hipMemsetAsync(bcnt, 0, 32768, stream);
    hipMemsetAsync(esumpart, 0, 8192 + 1048576, stream);           // esumpart + hidpart
    hipMemsetAsync(d_out, 0, (size_t)out_size * sizeof(float), stream);

    prep_weights<<<1, 512, 0, stream>>>(gW1, lW1, W1p, L1p);
    bucketA_kernel<<<EE / 256, 256, 0, stream>>>(ei, bcnt, btmp);
    bucket_scan_kernel<<<1, NBUCK, 0, stream>>>(bcnt, bbase);
    bucketB_kernel<<<NBUCK, 256, 0, stream>>>(btmp, bcnt, bbase, offs, csr);

    pq_gemm<<<NN / 128, 512, 0, stream>>>(x, W1p, gb1, nullptr, bat, PQ);
    global_edge<<<NN / (4 * NPWG), 256, 0, stream>>>(PQ, csr, offs, e, bat, hidpart, esumpart);
    pooled_t12_kernel<<<BB, 256, 0, stream>>>(hidpart, esumpart, gW2, gb2, lW1, T12);
    pq_gemm<<<NN / 128, 512, 0, stream>>>(x, L1p, lb1, T12, bat, PQ);   // -> PQL
    local_edge<<<NN / (4 * NPWL), 256, 0, stream>>>(PQ, csr, offs, lW2, lb2, (float*)d_out);
}

// Round 11
// 190.322 us; speedup vs baseline: 1.9012x; 1.0589x over previous
//
#include <hip/hip_runtime.h>
#include <hip/hip_bf16.h>

#define NN 51200
#define EE 819200
#define BB 64
#define NS 32
#define NPWG 8      // nodes per wave, global edge pass
#define NPWL 4      // nodes per wave, local edge pass
#define NBUCK 512   // dst-range buckets for scatter
#define NPB 100     // nodes per bucket = NN/NBUCK
#define CAP 4096    // bucket capacity (mean 1600, std ~40)
#define EPB 4096    // edges per block in bucketA multi-split

typedef __attribute__((ext_vector_type(8))) short short8;
typedef __attribute__((ext_vector_type(4))) float f32x4;

__device__ __forceinline__ ushort f2bf(float f) {
    unsigned int u = __float_as_uint(f);
    unsigned int r = (u + 0x7FFFu + ((u >> 16) & 1u)) >> 16;   // RNE, finite inputs
    return (ushort)r;
}
__device__ __forceinline__ unsigned int cvt_pk_bf16(float lo, float hi) {
    unsigned int r;
    asm("v_cvt_pk_bf16_f32 %0, %1, %2" : "=v"(r) : "v"(lo), "v"(hi));
    return r;
}

// ---------------- weight prep ----------------
__global__ void prep_weights(const float* __restrict__ gW1, const float* __restrict__ lW1,
                             ushort* __restrict__ W1p, ushort* __restrict__ L1p) {
    int tid = threadIdx.x;
    for (int idx = tid; idx < 64 * 256; idx += 512) {
        int i = idx & 7, c = (idx >> 3) & 255, q = idx >> 11;
        int k = (q >> 2) * 32 + (q & 3) * 8 + i;
        W1p[idx] = f2bf(c < 128 ? gW1[k * 128 + c] : gW1[(64 + k) * 128 + (c - 128)]);
        L1p[idx] = f2bf(c < 128 ? lW1[k * 128 + c] : lW1[(128 + k) * 128 + (c - 128)]);
    }
}

// ---------------- CSR build: LDS multi-split -> fixed-capacity buckets -> in-LDS counting sort ----------------
// phase A: per-block LDS binning; per-bucket contiguous 64B chunk writes (no 8x line amplification)
__global__ __launch_bounds__(512) void bucketA_kernel(const int* __restrict__ eidx,
                                                      int* __restrict__ bcnt,
                                                      int2* __restrict__ btmp) {
    __shared__ int2 sp[EPB];         // 32 KB
    __shared__ ushort sb[EPB];       //  8 KB
    __shared__ ushort perm[EPB];     //  8 KB
    __shared__ int cnts[NBUCK];      //  2 KB
    __shared__ int lofs[NBUCK];      //  2 KB
    __shared__ int lcur[NBUCK];      //  2 KB
    __shared__ int gbase[NBUCK];     //  2 KB
    const int tid = threadIdx.x;
    const int base = blockIdx.x * EPB;

    cnts[tid] = 0;
    __syncthreads();
    for (int i = tid; i < EPB; i += 512) {
        int d = eidx[EE + base + i], s = eidx[base + i];
        sp[i] = make_int2(s, d);
        int b = d / NPB;
        sb[i] = (ushort)b;
        atomicAdd(&cnts[b], 1);
    }
    __syncthreads();
    // inclusive scan over 512 bucket counts
    const int v = cnts[tid];
    lofs[tid] = v;
    __syncthreads();
    for (int o = 1; o < NBUCK; o <<= 1) {
        int u = (tid >= o) ? lofs[tid - o] : 0;
        __syncthreads();
        lofs[tid] += u;
        __syncthreads();
    }
    const int excl = lofs[tid] - v;
    lofs[tid] = excl;
    lcur[tid] = excl;
    gbase[tid] = (v > 0) ? atomicAdd(&bcnt[tid * 16], v) : 0;
    __syncthreads();
    // local permutation: bucket-contiguous order
    for (int i = tid; i < EPB; i += 512) {
        int pos = atomicAdd(&lcur[sb[i]], 1);
        perm[pos] = (ushort)i;
    }
    __syncthreads();
    // chunk write: thread tid owns bucket tid -> ~8 consecutive int2 (one cache line)
    {
        const int c = cnts[tid];
        const int lo = lofs[tid];
        int2* dst = btmp + (long)tid * CAP + gbase[tid];
        for (int j = 0; j < c; ++j) dst[j] = sp[perm[lo + j]];
    }
}

__global__ __launch_bounds__(512) void bucket_scan_kernel(const int* __restrict__ bcnt,
                                                          int* __restrict__ bbase) {
    __shared__ int s[NBUCK];
    const int t = threadIdx.x;
    int v = bcnt[t * 16];
    s[t] = v;
    __syncthreads();
    for (int o = 1; o < NBUCK; o <<= 1) {
        int u = (t >= o) ? s[t - o] : 0;
        __syncthreads();
        s[t] += u;
        __syncthreads();
    }
    bbase[t] = s[t] - v;   // exclusive
}

__global__ __launch_bounds__(256) void bucketB_kernel(const int2* __restrict__ btmp,
                                                      const int* __restrict__ bcnt,
                                                      const int* __restrict__ bbase,
                                                      int* __restrict__ offs,
                                                      int* __restrict__ csr) {
    __shared__ int lcnt[NPB];
    __shared__ int lofs[NPB];
    __shared__ int lcur[NPB];
    __shared__ int2 pairs[2048];
    const int bkt = blockIdx.x, tid = threadIdx.x;
    const int cnt = bcnt[bkt * 16];
    const int base = bbase[bkt];
    for (int j = tid; j < NPB; j += 256) lcnt[j] = 0;
    __syncthreads();
    for (int i = tid; i < cnt; i += 256) {
        int2 p = btmp[(long)bkt * CAP + i];
        if (i < 2048) pairs[i] = p;
        atomicAdd(&lcnt[p.y - bkt * NPB], 1);
    }
    __syncthreads();
    if (tid == 0) {
        int run = base;
        for (int j = 0; j < NPB; ++j) { lofs[j] = run; run += lcnt[j]; }
    }
    __syncthreads();
    for (int j = tid; j < NPB; j += 256) {
        lcur[j] = lofs[j];
        offs[bkt * NPB + j] = lofs[j];
    }
    if (bkt == NBUCK - 1 && tid == 0) offs[NN] = EE;
    __syncthreads();
    for (int i = tid; i < cnt; i += 256) {
        int2 p = (i < 2048) ? pairs[i] : btmp[(long)bkt * CAP + i];
        int pos = atomicAdd(&lcur[p.y - bkt * NPB], 1);
        csr[pos] = p.x;
    }
}

// ---------------- node-table GEMM: out[n][0:256] = bf16( x[n]@Wcat + bias_fold + T12[batch[n]] ) ----------------
__global__ __launch_bounds__(512) void pq_gemm(
        const float* __restrict__ x, const ushort* __restrict__ Wp,
        const float* __restrict__ bias1, const float* __restrict__ T12,
        const int* __restrict__ batch, ushort* __restrict__ out) {
    const int tid = threadIdx.x;
    const int w = tid >> 6, l = tid & 63, lr = l & 15, lg = l >> 4;
    const int node = blockIdx.x * 128 + w * 16 + lr;

    short8 xa[2];
#pragma unroll
    for (int ks = 0; ks < 2; ++ks) {
        const float4* bp = reinterpret_cast<const float4*>(x + (long)node * 64 + ks * 32 + lg * 8);
        float4 f0 = bp[0], f1 = bp[1];
        union { short8 s; unsigned int u[4]; } t;
        t.u[0] = cvt_pk_bf16(f0.x, f0.y);
        t.u[1] = cvt_pk_bf16(f0.z, f0.w);
        t.u[2] = cvt_pk_bf16(f1.x, f1.y);
        t.u[3] = cvt_pk_bf16(f1.z, f1.w);
        xa[ks] = t.s;
    }
    f32x4 acc[16];
#pragma unroll
    for (int t = 0; t < 16; ++t)
#pragma unroll
        for (int i = 0; i < 4; ++i)
            acc[t][i] = (t < 8) ? bias1[t * 16 + lg * 4 + i] : 0.f;
#pragma unroll
    for (int ks = 0; ks < 2; ++ks)
#pragma unroll
        for (int t = 0; t < 16; ++t) {
            short8 wf = *reinterpret_cast<const short8*>(Wp + (((ks * 4 + lg) * 256) + t * 16 + lr) * 8);
            acc[t] = __builtin_amdgcn_mfma_f32_16x16x32_bf16(wf, xa[ks], acc[t], 0, 0, 0);
        }
    if (T12) {
        const float* tp = T12 + (long)batch[node] * 256;
#pragma unroll
        for (int t = 0; t < 16; ++t)
#pragma unroll
            for (int i = 0; i < 4; ++i)
                acc[t][i] += tp[t * 16 + lg * 4 + i];
    }
#pragma unroll
    for (int t = 0; t < 16; ++t) {
        uint2 v;
        v.x = cvt_pk_bf16(acc[t][0], acc[t][1]);
        v.y = cvt_pk_bf16(acc[t][2], acc[t][3]);
        *reinterpret_cast<uint2*>(out + (long)node * 256 + t * 16 + lg * 4) = v;
    }
}

// ---------------- global edge pass (CSR): scalar control, 2 ch/lane, 16-deep gather batch ----------------
__global__ __launch_bounds__(256) void global_edge(
        const ushort* __restrict__ PQ, const int* __restrict__ csr,
        const int* __restrict__ offs, const float* __restrict__ e,
        const int* __restrict__ batch,
        float* __restrict__ hidpart, float* __restrict__ esumpart) {
    const int tid = threadIdx.x;
    const int w = tid >> 6, l = tid & 63;
    const int wid = blockIdx.x * 4 + w;
    const int node0 = __builtin_amdgcn_readfirstlane(wid * NPWG);
    const int slot = wid & (NS - 1);

    float accp0 = 0.f, accp1 = 0.f, eacc = 0.f;
    int curb = batch[node0];

    for (int n = 0; n < NPWG; ++n) {
        const int node = node0 + n;
        const int off  = offs[node];
        const int cnt  = offs[node + 1] - off;
        const int bb   = batch[node];
        const float ev = e[node];
        if (bb != curb) {
            float* hp = hidpart + (long)slot * (BB * 128) + curb * 128;
            atomicAdd(hp + 2 * l, accp0);
            atomicAdd(hp + 2 * l + 1, accp1);
            if (l == 0) atomicAdd(&esumpart[slot * BB + curb], eacc);
            accp0 = accp1 = eacc = 0.f;
            curb = bb;
        }
        if (cnt <= 0) continue;
        const unsigned int pdu = *reinterpret_cast<const unsigned int*>(PQ + (long)node * 256 + 2 * l);
        const float p0 = __uint_as_float(pdu << 16);
        const float p1 = __uint_as_float(pdu & 0xFFFF0000u);
        float h0 = 0.f, h1 = 0.f;
        int g = 0;
        for (; g + 16 <= cnt; g += 16) {        // 16 independent gathers in flight
            unsigned int qv[16];
#pragma unroll
            for (int k = 0; k < 16; ++k) {
                const int s = csr[off + g + k];
                qv[k] = *reinterpret_cast<const unsigned int*>(PQ + (long)s * 256 + 128 + 2 * l);
            }
#pragma unroll
            for (int k = 0; k < 16; ++k) {
                h0 += fmaxf(p0 + __uint_as_float(qv[k] << 16), 0.f);
                h1 += fmaxf(p1 + __uint_as_float(qv[k] & 0xFFFF0000u), 0.f);
            }
        }
        for (; g + 8 <= cnt; g += 8) {
            unsigned int qv[8];
#pragma unroll
            for (int k = 0; k < 8; ++k) {
                const int s = csr[off + g + k];
                qv[k] = *reinterpret_cast<const unsigned int*>(PQ + (long)s * 256 + 128 + 2 * l);
            }
#pragma unroll
            for (int k = 0; k < 8; ++k) {
                h0 += fmaxf(p0 + __uint_as_float(qv[k] << 16), 0.f);
                h1 += fmaxf(p1 + __uint_as_float(qv[k] & 0xFFFF0000u), 0.f);
            }
        }
        for (; g < cnt; ++g) {
            const int s = csr[off + g];
            const unsigned int qv = *reinterpret_cast<const unsigned int*>(PQ + (long)s * 256 + 128 + 2 * l);
            h0 += fmaxf(p0 + __uint_as_float(qv << 16), 0.f);
            h1 += fmaxf(p1 + __uint_as_float(qv & 0xFFFF0000u), 0.f);
        }
        accp0 += ev * h0; accp1 += ev * h1; eacc += ev * (float)cnt;
    }
    {   // final flush
        float* hp = hidpart + (long)slot * (BB * 128) + curb * 128;
        atomicAdd(hp + 2 * l, accp0);
        atomicAdd(hp + 2 * l + 1, accp1);
        if (l == 0) atomicAdd(&esumpart[slot * BB + curb], eacc);
    }
}

// ---------------- fused: hidsum reduce -> pooled (LDS only) -> T12 ----------------
__global__ __launch_bounds__(256) void pooled_t12_kernel(
        const float* __restrict__ hidpart, const float* __restrict__ esumpart,
        const float* __restrict__ gW2, const float* __restrict__ gb2,
        const float* __restrict__ lW1, float* __restrict__ T12) {
    __shared__ float hs[128];
    __shared__ float qacc[4][64];
    __shared__ float pb[64];
    __shared__ float esv;
    const int b = blockIdx.x, tid = threadIdx.x;
    if (tid < 128) {
        float s = 0.f;
        for (int sl = 0; sl < NS; ++sl) s += hidpart[(long)sl * (BB * 128) + b * 128 + tid];
        hs[tid] = s;
    } else if (tid == 128) {
        float s = 0.f;
        for (int sl = 0; sl < NS; ++sl) s += esumpart[sl * BB + b];
        esv = s;
    }
    __syncthreads();
    {
        int col = tid & 63, qr = tid >> 6;
        float a = 0.f;
        for (int k = qr * 32; k < qr * 32 + 32; ++k) a += hs[k] * gW2[k * 64 + col];
        qacc[qr][col] = a;
    }
    __syncthreads();
    if (tid < 64) pb[tid] = qacc[0][tid] + qacc[1][tid] + qacc[2][tid] + qacc[3][tid] + esv * gb2[tid];
    __syncthreads();
    const float* col = (tid < 128) ? (lW1 + 64 * 128 + tid) : (lW1 + 192 * 128 + (tid - 128));
    float acc = 0.f;
    for (int k = 0; k < 64; ++k) acc += pb[k] * col[k * 128];
    T12[b * 256 + tid] = acc;
}

// ---------------- local edge pass (CSR): scalar control, 2 ch/lane, 16-deep gather batch ----------------
__global__ __launch_bounds__(256) void local_edge(
        const ushort* __restrict__ PQL, const int* __restrict__ csr,
        const int* __restrict__ offs, const float* __restrict__ lW2,
        const float* __restrict__ lb2, float* __restrict__ out) {
    const int tid = threadIdx.x;
    const int w = tid >> 6, l = tid & 63;
    const int wid = blockIdx.x * 4 + w;
    const int node0 = __builtin_amdgcn_readfirstlane(wid * NPWL);
    const float w20 = lW2[2 * l], w21 = lW2[2 * l + 1];
    const float b2v = lb2[0];

    for (int n = 0; n < NPWL; ++n) {
        const int node = node0 + n;
        const int off = offs[node];
        const int cnt = offs[node + 1] - off;
        float dacc = 0.f;
        if (cnt > 0) {
            const unsigned int pdu = *reinterpret_cast<const unsigned int*>(PQL + (long)node * 256 + 2 * l);
            const float p0 = __uint_as_float(pdu << 16);
            const float p1 = __uint_as_float(pdu & 0xFFFF0000u);
            int g = 0;
            for (; g + 16 <= cnt; g += 16) {
                unsigned int qv[16];
#pragma unroll
                for (int k = 0; k < 16; ++k) {
                    const int s = csr[off + g + k];
                    qv[k] = *reinterpret_cast<const unsigned int*>(PQL + (long)s * 256 + 128 + 2 * l);
                }
#pragma unroll
                for (int k = 0; k < 16; ++k) {
                    dacc += fmaxf(p0 + __uint_as_float(qv[k] << 16), 0.f) * w20
                          + fmaxf(p1 + __uint_as_float(qv[k] & 0xFFFF0000u), 0.f) * w21;
                }
            }
            for (; g + 8 <= cnt; g += 8) {
                unsigned int qv[8];
#pragma unroll
                for (int k = 0; k < 8; ++k) {
                    const int s = csr[off + g + k];
                    qv[k] = *reinterpret_cast<const unsigned int*>(PQL + (long)s * 256 + 128 + 2 * l);
                }
#pragma unroll
                for (int k = 0; k < 8; ++k) {
                    dacc += fmaxf(p0 + __uint_as_float(qv[k] << 16), 0.f) * w20
                          + fmaxf(p1 + __uint_as_float(qv[k] & 0xFFFF0000u), 0.f) * w21;
                }
            }
            for (; g < cnt; ++g) {
                const int s = csr[off + g];
                const unsigned int qv = *reinterpret_cast<const unsigned int*>(PQL + (long)s * 256 + 128 + 2 * l);
                dacc += fmaxf(p0 + __uint_as_float(qv << 16), 0.f) * w20
                      + fmaxf(p1 + __uint_as_float(qv & 0xFFFF0000u), 0.f) * w21;
            }
            dacc += __shfl_xor(dacc, 1, 64);
            dacc += __shfl_xor(dacc, 2, 64);
            dacc += __shfl_xor(dacc, 4, 64);
            dacc += __shfl_xor(dacc, 8, 64);
            dacc += __shfl_xor(dacc, 16, 64);
            dacc += __shfl_xor(dacc, 32, 64);
        }
        if (l == 0) out[node] = dacc + (float)cnt * b2v;
    }
}

extern "C" void kernel_launch(void* const* d_in, const int* in_sizes, int n_in,
                              void* d_out, int out_size, void* d_ws, size_t ws_size,
                              hipStream_t stream) {
    const float* x   = (const float*)d_in[0];
    const float* e   = (const float*)d_in[1];
    const int*   ei  = (const int*)d_in[2];
    const int*   bat = (const int*)d_in[3];
    const float* gW1 = (const float*)d_in[4];
    const float* gb1 = (const float*)d_in[5];
    const float* gW2 = (const float*)d_in[6];
    const float* gb2 = (const float*)d_in[7];
    const float* lW1 = (const float*)d_in[8];
    const float* lb1 = (const float*)d_in[9];
    const float* lW2 = (const float*)d_in[10];
    const float* lb2 = (const float*)d_in[11];

    char* ws = (char*)d_ws;
    ushort* W1p     = (ushort*)(ws);                     //    32768 B
    ushort* L1p     = (ushort*)(ws + 32768);             //    32768 B
    float*  T12     = (float*)(ws + 65536);              //    65536 B
    float*  esumpart= (float*)(ws + 131072);             //     8192 B
    float*  hidpart = (float*)(ws + 139264);             //  1048576 B
    int*    offs    = (int*)(ws + 1187840);              //   204832 B (51201 ints)
    int*    bcnt    = (int*)(ws + 1392672);              //    32768 B (512 line-padded)
    int*    bbase   = (int*)(ws + 1425440);              //     2048 B
    int*    csr     = (int*)(ws + 1427488);              //  3276800 B
    ushort* PQ      = (ushort*)(ws + 4704288);           // 26214400 B (btmp overlays; reused for PQL)
    int2*   btmp    = (int2*)PQ;                         // 512*4096*8 = 16777216 B, consumed before pq_gemm

    hipMemsetAsync(bcnt, 0, 32768, stream);
    hipMemsetAsync(esumpart, 0, 8192 + 1048576, stream);           // esumpart + hidpart
    hipMemsetAsync(d_out, 0, (size_t)out_size * sizeof(float), stream);

    prep_weights<<<1, 512, 0, stream>>>(gW1, lW1, W1p, L1p);
    bucketA_kernel<<<EE / EPB, 512, 0, stream>>>(ei, bcnt, btmp);
    bucket_scan_kernel<<<1, NBUCK, 0, stream>>>(bcnt, bbase);
    bucketB_kernel<<<NBUCK, 256, 0, stream>>>(btmp, bcnt, bbase, offs, csr);

    pq_gemm<<<NN / 128, 512, 0, stream>>>(x, W1p, gb1, nullptr, bat, PQ);
    global_edge<<<NN / (4 * NPWG), 256, 0, stream>>>(PQ, csr, offs, e, bat, hidpart, esumpart);
    pooled_t12_kernel<<<BB, 256, 0, stream>>>(hidpart, esumpart, gW2, gb2, lW1, T12);
    pq_gemm<<<NN / 128, 512, 0, stream>>>(x, L1p, lb1, T12, bat, PQ);   // -> PQL
    local_edge<<<NN / (4 * NPWL), 256, 0, stream>>>(PQ, csr, offs, lW2, lb2, (float*)d_out);
}

// Round 12
// 180.760 us; speedup vs baseline: 2.0017x; 1.0529x over previous
//
#include <hip/hip_runtime.h>
#include <hip/hip_bf16.h>

#define NN 51200
#define EE 819200
#define BB 64
#define NS 32
#define NPWG 4      // nodes per wave, global edge pass
#define NPWL 4      // nodes per wave, local edge pass
#define NBUCK 512   // dst-range buckets for scatter
#define NPB 100     // nodes per bucket = NN/NBUCK
#define CAP 4096    // bucket capacity (mean 1600, std ~40)
#define EPB 4096    // edges per block in bucketA multi-split

typedef __attribute__((ext_vector_type(8))) short short8;
typedef __attribute__((ext_vector_type(4))) float f32x4;

__device__ __forceinline__ ushort f2bf(float f) {
    unsigned int u = __float_as_uint(f);
    unsigned int r = (u + 0x7FFFu + ((u >> 16) & 1u)) >> 16;   // RNE, finite inputs
    return (ushort)r;
}
__device__ __forceinline__ unsigned int cvt_pk_bf16(float lo, float hi) {
    unsigned int r;
    asm("v_cvt_pk_bf16_f32 %0, %1, %2" : "=v"(r) : "v"(lo), "v"(hi));
    return r;
}

// ---------------- weight prep ----------------
__global__ void prep_weights(const float* __restrict__ gW1, const float* __restrict__ lW1,
                             ushort* __restrict__ W1p, ushort* __restrict__ L1p) {
    int tid = threadIdx.x;
    for (int idx = tid; idx < 64 * 256; idx += 512) {
        int i = idx & 7, c = (idx >> 3) & 255, q = idx >> 11;
        int k = (q >> 2) * 32 + (q & 3) * 8 + i;
        W1p[idx] = f2bf(c < 128 ? gW1[k * 128 + c] : gW1[(64 + k) * 128 + (c - 128)]);
        L1p[idx] = f2bf(c < 128 ? lW1[k * 128 + c] : lW1[(128 + k) * 128 + (c - 128)]);
    }
}

// ---------------- CSR build: LDS multi-split -> fixed-capacity buckets -> in-LDS counting sort ----------------
__global__ __launch_bounds__(512) void bucketA_kernel(const int* __restrict__ eidx,
                                                      int* __restrict__ bcnt,
                                                      int2* __restrict__ btmp) {
    __shared__ int2 sp[EPB];         // 32 KB
    __shared__ ushort sb[EPB];       //  8 KB
    __shared__ ushort perm[EPB];     //  8 KB
    __shared__ int cnts[NBUCK];      //  2 KB
    __shared__ int lofs[NBUCK];      //  2 KB
    __shared__ int lcur[NBUCK];      //  2 KB
    __shared__ int gbase[NBUCK];     //  2 KB
    const int tid = threadIdx.x;
    const int base = blockIdx.x * EPB;

    cnts[tid] = 0;
    __syncthreads();
    for (int i = tid; i < EPB; i += 512) {
        int d = eidx[EE + base + i], s = eidx[base + i];
        sp[i] = make_int2(s, d);
        int b = d / NPB;
        sb[i] = (ushort)b;
        atomicAdd(&cnts[b], 1);
    }
    __syncthreads();
    const int v = cnts[tid];
    lofs[tid] = v;
    __syncthreads();
    for (int o = 1; o < NBUCK; o <<= 1) {
        int u = (tid >= o) ? lofs[tid - o] : 0;
        __syncthreads();
        lofs[tid] += u;
        __syncthreads();
    }
    const int excl = lofs[tid] - v;
    lofs[tid] = excl;
    lcur[tid] = excl;
    gbase[tid] = (v > 0) ? atomicAdd(&bcnt[tid * 16], v) : 0;
    __syncthreads();
    for (int i = tid; i < EPB; i += 512) {
        int pos = atomicAdd(&lcur[sb[i]], 1);
        perm[pos] = (ushort)i;
    }
    __syncthreads();
    {
        const int c = cnts[tid];
        const int lo = lofs[tid];
        int2* dst = btmp + (long)tid * CAP + gbase[tid];
        for (int j = 0; j < c; ++j) dst[j] = sp[perm[lo + j]];
    }
}

__global__ __launch_bounds__(512) void bucket_scan_kernel(const int* __restrict__ bcnt,
                                                          int* __restrict__ bbase) {
    __shared__ int s[NBUCK];
    const int t = threadIdx.x;
    int v = bcnt[t * 16];
    s[t] = v;
    __syncthreads();
    for (int o = 1; o < NBUCK; o <<= 1) {
        int u = (t >= o) ? s[t - o] : 0;
        __syncthreads();
        s[t] += u;
        __syncthreads();
    }
    bbase[t] = s[t] - v;   // exclusive
}

__global__ __launch_bounds__(256) void bucketB_kernel(const int2* __restrict__ btmp,
                                                      const int* __restrict__ bcnt,
                                                      const int* __restrict__ bbase,
                                                      int* __restrict__ offs,
                                                      int* __restrict__ csr) {
    __shared__ int lcnt[NPB];
    __shared__ int lofs[NPB];
    __shared__ int lcur[NPB];
    __shared__ int2 pairs[2048];
    const int bkt = blockIdx.x, tid = threadIdx.x;
    const int cnt = bcnt[bkt * 16];
    const int base = bbase[bkt];
    for (int j = tid; j < NPB; j += 256) lcnt[j] = 0;
    __syncthreads();
    for (int i = tid; i < cnt; i += 256) {
        int2 p = btmp[(long)bkt * CAP + i];
        if (i < 2048) pairs[i] = p;
        atomicAdd(&lcnt[p.y - bkt * NPB], 1);
    }
    __syncthreads();
    if (tid == 0) {
        int run = base;
        for (int j = 0; j < NPB; ++j) { lofs[j] = run; run += lcnt[j]; }
    }
    __syncthreads();
    for (int j = tid; j < NPB; j += 256) {
        lcur[j] = lofs[j];
        offs[bkt * NPB + j] = lofs[j];
    }
    if (bkt == NBUCK - 1 && tid == 0) offs[NN] = EE;
    __syncthreads();
    for (int i = tid; i < cnt; i += 256) {
        int2 p = (i < 2048) ? pairs[i] : btmp[(long)bkt * CAP + i];
        int pos = atomicAdd(&lcur[p.y - bkt * NPB], 1);
        csr[pos] = p.x;
    }
}

// ---------------- node-table GEMM: out[n][0:256] = bf16( x[n]@Wcat + bias_fold + T12[batch[n]] ) ----------------
__global__ __launch_bounds__(512) void pq_gemm(
        const float* __restrict__ x, const ushort* __restrict__ Wp,
        const float* __restrict__ bias1, const float* __restrict__ T12,
        const int* __restrict__ batch, ushort* __restrict__ out) {
    const int tid = threadIdx.x;
    const int w = tid >> 6, l = tid & 63, lr = l & 15, lg = l >> 4;
    const int node = blockIdx.x * 128 + w * 16 + lr;

    short8 xa[2];
#pragma unroll
    for (int ks = 0; ks < 2; ++ks) {
        const float4* bp = reinterpret_cast<const float4*>(x + (long)node * 64 + ks * 32 + lg * 8);
        float4 f0 = bp[0], f1 = bp[1];
        union { short8 s; unsigned int u[4]; } t;
        t.u[0] = cvt_pk_bf16(f0.x, f0.y);
        t.u[1] = cvt_pk_bf16(f0.z, f0.w);
        t.u[2] = cvt_pk_bf16(f1.x, f1.y);
        t.u[3] = cvt_pk_bf16(f1.z, f1.w);
        xa[ks] = t.s;
    }
    f32x4 acc[16];
#pragma unroll
    for (int t = 0; t < 16; ++t)
#pragma unroll
        for (int i = 0; i < 4; ++i)
            acc[t][i] = (t < 8) ? bias1[t * 16 + lg * 4 + i] : 0.f;
#pragma unroll
    for (int ks = 0; ks < 2; ++ks)
#pragma unroll
        for (int t = 0; t < 16; ++t) {
            short8 wf = *reinterpret_cast<const short8*>(Wp + (((ks * 4 + lg) * 256) + t * 16 + lr) * 8);
            acc[t] = __builtin_amdgcn_mfma_f32_16x16x32_bf16(wf, xa[ks], acc[t], 0, 0, 0);
        }
    if (T12) {
        const float* tp = T12 + (long)batch[node] * 256;
#pragma unroll
        for (int t = 0; t < 16; ++t)
#pragma unroll
            for (int i = 0; i < 4; ++i)
                acc[t][i] += tp[t * 16 + lg * 4 + i];
    }
#pragma unroll
    for (int t = 0; t < 16; ++t) {
        uint2 v;
        v.x = cvt_pk_bf16(acc[t][0], acc[t][1]);
        v.y = cvt_pk_bf16(acc[t][2], acc[t][3]);
        *reinterpret_cast<uint2*>(out + (long)node * 256 + t * 16 + lg * 4) = v;
    }
}

// ---------------- global edge pass (CSR): scalar control, 2 ch/lane, 8-deep gather batch ----------------
__global__ __launch_bounds__(256) void global_edge(
        const ushort* __restrict__ PQ, const int* __restrict__ csr,
        const int* __restrict__ offs, const float* __restrict__ e,
        const int* __restrict__ batch,
        float* __restrict__ hidpart, float* __restrict__ esumpart) {
    const int tid = threadIdx.x;
    const int w = tid >> 6, l = tid & 63;
    const int wid = blockIdx.x * 4 + w;
    const int node0 = __builtin_amdgcn_readfirstlane(wid * NPWG);
    const int slot = wid & (NS - 1);

    float accp0 = 0.f, accp1 = 0.f, eacc = 0.f;
    int curb = batch[node0];

    for (int n = 0; n < NPWG; ++n) {
        const int node = node0 + n;
        const int off  = offs[node];
        const int cnt  = offs[node + 1] - off;
        const int bb   = batch[node];
        const float ev = e[node];
        if (bb != curb) {
            float* hp = hidpart + (long)slot * (BB * 128) + curb * 128;
            atomicAdd(hp + 2 * l, accp0);
            atomicAdd(hp + 2 * l + 1, accp1);
            if (l == 0) atomicAdd(&esumpart[slot * BB + curb], eacc);
            accp0 = accp1 = eacc = 0.f;
            curb = bb;
        }
        if (cnt <= 0) continue;
        const unsigned int pdu = *reinterpret_cast<const unsigned int*>(PQ + (long)node * 256 + 2 * l);
        const float p0 = __uint_as_float(pdu << 16);
        const float p1 = __uint_as_float(pdu & 0xFFFF0000u);
        float h0 = 0.f, h1 = 0.f;
        int g = 0;
        for (; g + 8 <= cnt; g += 8) {          // 8 independent gathers in flight
            unsigned int qv[8];
#pragma unroll
            for (int k = 0; k < 8; ++k) {
                const int s = csr[off + g + k];
                qv[k] = *reinterpret_cast<const unsigned int*>(PQ + (long)s * 256 + 128 + 2 * l);
            }
#pragma unroll
            for (int k = 0; k < 8; ++k) {
                h0 += fmaxf(p0 + __uint_as_float(qv[k] << 16), 0.f);
                h1 += fmaxf(p1 + __uint_as_float(qv[k] & 0xFFFF0000u), 0.f);
            }
        }
        for (; g < cnt; ++g) {
            const int s = csr[off + g];
            const unsigned int qv = *reinterpret_cast<const unsigned int*>(PQ + (long)s * 256 + 128 + 2 * l);
            h0 += fmaxf(p0 + __uint_as_float(qv << 16), 0.f);
            h1 += fmaxf(p1 + __uint_as_float(qv & 0xFFFF0000u), 0.f);
        }
        accp0 += ev * h0; accp1 += ev * h1; eacc += ev * (float)cnt;
    }
    {   // final flush
        float* hp = hidpart + (long)slot * (BB * 128) + curb * 128;
        atomicAdd(hp + 2 * l, accp0);
        atomicAdd(hp + 2 * l + 1, accp1);
        if (l == 0) atomicAdd(&esumpart[slot * BB + curb], eacc);
    }
}

// ---------------- fused: hidsum reduce -> pooled (LDS only) -> T12 ----------------
__global__ __launch_bounds__(256) void pooled_t12_kernel(
        const float* __restrict__ hidpart, const float* __restrict__ esumpart,
        const float* __restrict__ gW2, const float* __restrict__ gb2,
        const float* __restrict__ lW1, float* __restrict__ T12) {
    __shared__ float hs[128];
    __shared__ float qacc[4][64];
    __shared__ float pb[64];
    __shared__ float esv;
    const int b = blockIdx.x, tid = threadIdx.x;
    if (tid < 128) {
        float s = 0.f;
        for (int sl = 0; sl < NS; ++sl) s += hidpart[(long)sl * (BB * 128) + b * 128 + tid];
        hs[tid] = s;
    } else if (tid == 128) {
        float s = 0.f;
        for (int sl = 0; sl < NS; ++sl) s += esumpart[sl * BB + b];
        esv = s;
    }
    __syncthreads();
    {
        int col = tid & 63, qr = tid >> 6;
        float a = 0.f;
        for (int k = qr * 32; k < qr * 32 + 32; ++k) a += hs[k] * gW2[k * 64 + col];
        qacc[qr][col] = a;
    }
    __syncthreads();
    if (tid < 64) pb[tid] = qacc[0][tid] + qacc[1][tid] + qacc[2][tid] + qacc[3][tid] + esv * gb2[tid];
    __syncthreads();
    const float* col = (tid < 128) ? (lW1 + 64 * 128 + tid) : (lW1 + 192 * 128 + (tid - 128));
    float acc = 0.f;
    for (int k = 0; k < 64; ++k) acc += pb[k] * col[k * 128];
    T12[b * 256 + tid] = acc;
}

// ---------------- local edge pass (CSR): scalar control, 2 ch/lane, 8-deep gather batch ----------------
__global__ __launch_bounds__(256) void local_edge(
        const ushort* __restrict__ PQL, const int* __restrict__ csr,
        const int* __restrict__ offs, const float* __restrict__ lW2,
        const float* __restrict__ lb2, float* __restrict__ out) {
    const int tid = threadIdx.x;
    const int w = tid >> 6, l = tid & 63;
    const int wid = blockIdx.x * 4 + w;
    const int node0 = __builtin_amdgcn_readfirstlane(wid * NPWL);
    const float w20 = lW2[2 * l], w21 = lW2[2 * l + 1];
    const float b2v = lb2[0];

    for (int n = 0; n < NPWL; ++n) {
        const int node = node0 + n;
        const int off = offs[node];
        const int cnt = offs[node + 1] - off;
        float dacc = 0.f;
        if (cnt > 0) {
            const unsigned int pdu = *reinterpret_cast<const unsigned int*>(PQL + (long)node * 256 + 2 * l);
            const float p0 = __uint_as_float(pdu << 16);
            const float p1 = __uint_as_float(pdu & 0xFFFF0000u);
            int g = 0;
            for (; g + 8 <= cnt; g += 8) {
                unsigned int qv[8];
#pragma unroll
                for (int k = 0; k < 8; ++k) {
                    const int s = csr[off + g + k];
                    qv[k] = *reinterpret_cast<const unsigned int*>(PQL + (long)s * 256 + 128 + 2 * l);
                }
#pragma unroll
                for (int k = 0; k < 8; ++k) {
                    dacc += fmaxf(p0 + __uint_as_float(qv[k] << 16), 0.f) * w20
                          + fmaxf(p1 + __uint_as_float(qv[k] & 0xFFFF0000u), 0.f) * w21;
                }
            }
            for (; g < cnt; ++g) {
                const int s = csr[off + g];
                const unsigned int qv = *reinterpret_cast<const unsigned int*>(PQL + (long)s * 256 + 128 + 2 * l);
                dacc += fmaxf(p0 + __uint_as_float(qv << 16), 0.f) * w20
                      + fmaxf(p1 + __uint_as_float(qv & 0xFFFF0000u), 0.f) * w21;
            }
            dacc += __shfl_xor(dacc, 1, 64);
            dacc += __shfl_xor(dacc, 2, 64);
            dacc += __shfl_xor(dacc, 4, 64);
            dacc += __shfl_xor(dacc, 8, 64);
            dacc += __shfl_xor(dacc, 16, 64);
            dacc += __shfl_xor(dacc, 32, 64);
        }
        if (l == 0) out[node] = dacc + (float)cnt * b2v;
    }
}

extern "C" void kernel_launch(void* const* d_in, const int* in_sizes, int n_in,
                              void* d_out, int out_size, void* d_ws, size_t ws_size,
                              hipStream_t stream) {
    const float* x   = (const float*)d_in[0];
    const float* e   = (const float*)d_in[1];
    const int*   ei  = (const int*)d_in[2];
    const int*   bat = (const int*)d_in[3];
    const float* gW1 = (const float*)d_in[4];
    const float* gb1 = (const float*)d_in[5];
    const float* gW2 = (const float*)d_in[6];
    const float* gb2 = (const float*)d_in[7];
    const float* lW1 = (const float*)d_in[8];
    const float* lb1 = (const float*)d_in[9];
    const float* lW2 = (const float*)d_in[10];
    const float* lb2 = (const float*)d_in[11];

    char* ws = (char*)d_ws;
    ushort* W1p     = (ushort*)(ws);                     //    32768 B
    ushort* L1p     = (ushort*)(ws + 32768);             //    32768 B
    float*  T12     = (float*)(ws + 65536);              //    65536 B
    float*  esumpart= (float*)(ws + 131072);             //     8192 B
    float*  hidpart = (float*)(ws + 139264);             //  1048576 B
    int*    offs    = (int*)(ws + 1187840);              //   204832 B (51201 ints)
    int*    bcnt    = (int*)(ws + 1392672);              //    32768 B (512 line-padded)
    int*    bbase   = (int*)(ws + 1425440);              //     2048 B
    int*    csr     = (int*)(ws + 1427488);              //  3276800 B
    ushort* PQ      = (ushort*)(ws + 4704288);           // 26214400 B (btmp overlays; reused for PQL)
    int2*   btmp    = (int2*)PQ;                         // 512*4096*8 = 16777216 B, consumed before pq_gemm

    hipMemsetAsync(bcnt, 0, 32768, stream);
    hipMemsetAsync(esumpart, 0, 8192 + 1048576, stream);           // esumpart + hidpart
    hipMemsetAsync(d_out, 0, (size_t)out_size * sizeof(float), stream);

    prep_weights<<<1, 512, 0, stream>>>(gW1, lW1, W1p, L1p);
    bucketA_kernel<<<EE / EPB, 512, 0, stream>>>(ei, bcnt, btmp);
    bucket_scan_kernel<<<1, NBUCK, 0, stream>>>(bcnt, bbase);
    bucketB_kernel<<<NBUCK, 256, 0, stream>>>(btmp, bcnt, bbase, offs, csr);

    pq_gemm<<<NN / 128, 512, 0, stream>>>(x, W1p, gb1, nullptr, bat, PQ);
    global_edge<<<NN / (4 * NPWG), 256, 0, stream>>>(PQ, csr, offs, e, bat, hidpart, esumpart);
    pooled_t12_kernel<<<BB, 256, 0, stream>>>(hidpart, esumpart, gW2, gb2, lW1, T12);
    pq_gemm<<<NN / 128, 512, 0, stream>>>(x, L1p, lb1, T12, bat, PQ);   // -> PQL
    local_edge<<<NN / (4 * NPWL), 256, 0, stream>>>(PQ, csr, offs, lW2, lb2, (float*)d_out);
}